// Round 1
// baseline (1434.493 us; speedup 1.0000x reference)
//
#include <hip/hip_runtime.h>
#include <math.h>

#define D_MODEL 1024
#define NHEADS  16
#define DK      64
#define SEQ     2048
#define BATCH   2
#define MROWS   (BATCH*SEQ)   // 4096

// ---------------------------------------------------------------------------
// Tiled fp32 GEMM: out[m][n] = sum_k A[m][k] * W[n][k]   (W stored [n][k])
// Tile 64x64, K-step 32, 256 threads, 4x4 outputs per thread.
// mode 0: QKV projection epilogue -> RoPE (z=0,1) + [b][h][s][d] layout
// mode 1: plain row-major write (Wo projection)
// ---------------------------------------------------------------------------
__global__ __launch_bounds__(256) void gemm_proj(
    const float* __restrict__ A,
    const float* __restrict__ W0, const float* __restrict__ W1, const float* __restrict__ W2,
    float* __restrict__ D0, float* __restrict__ D1, float* __restrict__ D2,
    const int* __restrict__ pos, int mode)
{
    __shared__ float As[64][33];
    __shared__ float Bs[64][33];

    const int z = blockIdx.z;
    const float* Wm = (z == 0) ? W0 : ((z == 1) ? W1 : W2);
    float* D       = (z == 0) ? D0 : ((z == 1) ? D1 : D2);

    const int n0 = blockIdx.x * 64;
    const int m0 = blockIdx.y * 64;
    const int tid = threadIdx.x;
    const int tx = tid & 15;        // 16 col-groups
    const int ty = tid >> 4;        // 16 row-groups

    float acc[4][4] = {};

    for (int k0 = 0; k0 < D_MODEL; k0 += 32) {
        __syncthreads();
        // Load A tile (64x32) and W tile (64x32): 512 float4 each, 2 per thread
        #pragma unroll
        for (int it = 0; it < 2; ++it) {
            const int q = tid + it * 256;     // float4 index
            const int r = q >> 3;             // row 0..63
            const int c = (q & 7) * 4;        // col 0..28
            const float4 f = *(const float4*)(A  + (size_t)(m0 + r) * D_MODEL + k0 + c);
            As[r][c+0] = f.x; As[r][c+1] = f.y; As[r][c+2] = f.z; As[r][c+3] = f.w;
            const float4 g = *(const float4*)(Wm + (size_t)(n0 + r) * D_MODEL + k0 + c);
            Bs[r][c+0] = g.x; Bs[r][c+1] = g.y; Bs[r][c+2] = g.z; Bs[r][c+3] = g.w;
        }
        __syncthreads();

        #pragma unroll
        for (int kk = 0; kk < 32; ++kk) {
            float a[4], b[4];
            #pragma unroll
            for (int i = 0; i < 4; ++i) a[i] = As[ty*4 + i][kk];
            #pragma unroll
            for (int j = 0; j < 4; ++j) b[j] = Bs[tx*4 + j][kk];
            #pragma unroll
            for (int i = 0; i < 4; ++i)
                #pragma unroll
                for (int j = 0; j < 4; ++j)
                    acc[i][j] += a[i] * b[j];
        }
    }

    if (mode == 1) {
        // plain row-major output [m][n]
        #pragma unroll
        for (int i = 0; i < 4; ++i) {
            const int m = m0 + ty*4 + i;
            #pragma unroll
            for (int j = 0; j < 4; ++j) {
                D[(size_t)m * D_MODEL + n0 + tx*4 + j] = acc[i][j];
            }
        }
        return;
    }

    // mode 0: QKV.  Column c0..c0+3 all lie inside one head (c0 % 4 == 0).
    const int c0 = n0 + tx*4;
    const int h  = c0 >> 6;       // head
    const int r0 = c0 & 63;       // head-dim base (even)

    #pragma unroll
    for (int i = 0; i < 4; ++i) {
        const int m = m0 + ty*4 + i;
        const int b = m >> 11;          // / SEQ
        const int s = m & (SEQ - 1);
        float* dst = D + (((size_t)b * NHEADS + h) * SEQ + s) * DK;

        if (z == 2) {
            // V: no RoPE
            #pragma unroll
            for (int j = 0; j < 4; ++j) dst[r0 + j] = acc[i][j];
        } else {
            const float p = (float)pos[s];
            #pragma unroll
            for (int jp = 0; jp < 4; jp += 2) {
                const int rr = r0 + jp;          // even
                const int fi = rr >> 1;          // pair index 0..31
                const float freq = powf(10000.0f, -(float)fi * (1.0f / 32.0f));
                const float ang  = p * freq;
                const float cs = cosf(ang), sn = sinf(ang);
                const float x1 = acc[i][jp], x2 = acc[i][jp + 1];
                dst[rr]     = x1 * cs - x2 * sn;
                dst[rr + 1] = x1 * sn + x2 * cs;
            }
        }
    }
}

// ---------------------------------------------------------------------------
// Causal flash attention, fp32.
// Q,K,V in [b][h][s][d] (d=64).  One block = one (b,h) x 64-query tile.
// 256 threads: thread (ty,tx) owns 4 q-rows x 4 cols.
// Output written to attn_out in [b][s][h*64+d] layout (ready for Wo GEMM).
// ---------------------------------------------------------------------------
__global__ __launch_bounds__(256) void attn_fwd(
    const float* __restrict__ Q, const float* __restrict__ K,
    const float* __restrict__ V, float* __restrict__ AO)
{
    __shared__ float Qs[64][65];
    __shared__ float Ks[64][65];
    __shared__ float Vs[64][65];
    __shared__ float Ps[64][65];

    const int bh = blockIdx.y;
    const int qt = blockIdx.x;
    const int q0 = qt * 64;
    const float* Qb = Q + (size_t)bh * SEQ * DK;
    const float* Kb = K + (size_t)bh * SEQ * DK;
    const float* Vb = V + (size_t)bh * SEQ * DK;

    const int tid = threadIdx.x;
    const int tx = tid & 15;
    const int ty = tid >> 4;

    // Load Q tile: 64x64 = 1024 float4, 4 per thread
    #pragma unroll
    for (int it = 0; it < 4; ++it) {
        const int q = tid + it * 256;
        const int r = q >> 4;
        const int c = (q & 15) * 4;
        const float4 f = *(const float4*)(Qb + (size_t)(q0 + r) * DK + c);
        Qs[r][c+0] = f.x; Qs[r][c+1] = f.y; Qs[r][c+2] = f.z; Qs[r][c+3] = f.w;
    }

    float o[4][4] = {};
    float m_[4], l_[4];
    #pragma unroll
    for (int i = 0; i < 4; ++i) { m_[i] = -INFINITY; l_[i] = 0.0f; }

    for (int kt = 0; kt <= qt; ++kt) {
        __syncthreads();   // previous iter done with Ks/Vs/Ps
        const int k0 = kt * 64;
        #pragma unroll
        for (int it = 0; it < 4; ++it) {
            const int q = tid + it * 256;
            const int r = q >> 4;
            const int c = (q & 15) * 4;
            const float4 f = *(const float4*)(Kb + (size_t)(k0 + r) * DK + c);
            Ks[r][c+0] = f.x; Ks[r][c+1] = f.y; Ks[r][c+2] = f.z; Ks[r][c+3] = f.w;
            const float4 g = *(const float4*)(Vb + (size_t)(k0 + r) * DK + c);
            Vs[r][c+0] = g.x; Vs[r][c+1] = g.y; Vs[r][c+2] = g.z; Vs[r][c+3] = g.w;
        }
        __syncthreads();

        // S = Q K^T  (4x4 per thread)
        float sv[4][4] = {};
        #pragma unroll
        for (int kk = 0; kk < 64; ++kk) {
            float a[4], b[4];
            #pragma unroll
            for (int i = 0; i < 4; ++i) a[i] = Qs[ty*4 + i][kk];
            #pragma unroll
            for (int j = 0; j < 4; ++j) b[j] = Ks[tx*4 + j][kk];
            #pragma unroll
            for (int i = 0; i < 4; ++i)
                #pragma unroll
                for (int j = 0; j < 4; ++j)
                    sv[i][j] += a[i] * b[j];
        }

        const float scale = 0.125f;   // 1/sqrt(64)
        #pragma unroll
        for (int i = 0; i < 4; ++i)
            #pragma unroll
            for (int j = 0; j < 4; ++j)
                sv[i][j] *= scale;

        if (kt == qt) {
            // causal mask on diagonal tile
            #pragma unroll
            for (int i = 0; i < 4; ++i) {
                const int qi = q0 + ty*4 + i;
                #pragma unroll
                for (int j = 0; j < 4; ++j) {
                    const int kj = k0 + tx*4 + j;
                    if (kj > qi) sv[i][j] = -1e30f;
                }
            }
        }

        // online softmax update
        float alpha[4];
        #pragma unroll
        for (int i = 0; i < 4; ++i) {
            float rm = fmaxf(fmaxf(sv[i][0], sv[i][1]), fmaxf(sv[i][2], sv[i][3]));
            #pragma unroll
            for (int off = 1; off < 16; off <<= 1)
                rm = fmaxf(rm, __shfl_xor(rm, off));
            const float newm = fmaxf(m_[i], rm);
            alpha[i] = expf(m_[i] - newm);   // -inf - finite -> 0 on first tile
            float rs = 0.0f;
            #pragma unroll
            for (int j = 0; j < 4; ++j) {
                sv[i][j] = expf(sv[i][j] - newm);
                rs += sv[i][j];
            }
            #pragma unroll
            for (int off = 1; off < 16; off <<= 1)
                rs += __shfl_xor(rs, off);
            l_[i] = l_[i] * alpha[i] + rs;
            m_[i] = newm;
            #pragma unroll
            for (int j = 0; j < 4; ++j) o[i][j] *= alpha[i];
        }

        // stage P into LDS for the PV micro-GEMM
        #pragma unroll
        for (int i = 0; i < 4; ++i)
            #pragma unroll
            for (int j = 0; j < 4; ++j)
                Ps[ty*4 + i][tx*4 + j] = sv[i][j];
        __syncthreads();

        // O += P V
        #pragma unroll
        for (int kk = 0; kk < 64; ++kk) {
            float a[4], b[4];
            #pragma unroll
            for (int i = 0; i < 4; ++i) a[i] = Ps[ty*4 + i][kk];
            #pragma unroll
            for (int j = 0; j < 4; ++j) b[j] = Vs[kk][tx*4 + j];
            #pragma unroll
            for (int i = 0; i < 4; ++i)
                #pragma unroll
                for (int j = 0; j < 4; ++j)
                    o[i][j] += a[i] * b[j];
        }
    }

    // finalize + write out in [b][s][h*64+d] layout
    const int b = bh >> 4;
    const int h = bh & 15;
    #pragma unroll
    for (int i = 0; i < 4; ++i) {
        const int s = q0 + ty*4 + i;
        const float inv_l = 1.0f / l_[i];
        float* dst = AO + ((size_t)b * SEQ + s) * D_MODEL + h * DK + tx*4;
        #pragma unroll
        for (int j = 0; j < 4; ++j) dst[j] = o[i][j] * inv_l;
    }
}

// ---------------------------------------------------------------------------
extern "C" void kernel_launch(void* const* d_in, const int* in_sizes, int n_in,
                              void* d_out, int out_size, void* d_ws, size_t ws_size,
                              hipStream_t stream)
{
    const float* x   = (const float*)d_in[0];
    const int*   pos = (const int*)  d_in[1];
    const float* Wq  = (const float*)d_in[2];
    const float* Wk  = (const float*)d_in[3];
    const float* Wv  = (const float*)d_in[4];
    const float* Wo  = (const float*)d_in[5];
    float* out = (float*)d_out;

    float* ws = (float*)d_ws;
    const size_t PER = (size_t)BATCH * NHEADS * SEQ * DK;   // 4,194,304 floats
    float* Q  = ws;
    float* K  = Q + PER;
    float* V  = K + PER;
    float* AO = V + PER;

    dim3 blk(256);

    // QKV projections + RoPE (z = 0:Q, 1:K, 2:V)
    gemm_proj<<<dim3(D_MODEL/64, MROWS/64, 3), blk, 0, stream>>>(
        x, Wq, Wk, Wv, Q, K, V, pos, 0);

    // causal flash attention
    attn_fwd<<<dim3(SEQ/64, BATCH*NHEADS), blk, 0, stream>>>(Q, K, V, AO);

    // output projection
    gemm_proj<<<dim3(D_MODEL/64, MROWS/64, 1), blk, 0, stream>>>(
        AO, Wo, Wo, Wo, out, out, out, pos, 1);
}

// Round 2
// 218.080 us; speedup vs baseline: 6.5778x; 6.5778x over previous
//
#include <hip/hip_runtime.h>
#include <math.h>

#define SEQ 2048
#define NH  16
#define DKH 64
#define DM  1024
#define MR  4096   // BATCH*SEQ

using bf16x8 = __attribute__((ext_vector_type(8))) short;
using f32x4  = __attribute__((ext_vector_type(4))) float;

__device__ __forceinline__ ushort f2b(float f) {
  unsigned u = __float_as_uint(f);
  return (ushort)((u + 0x7fffu + ((u >> 16) & 1u)) >> 16);
}

__device__ __forceinline__ void gll16(const void* g, void* l) {
  __builtin_amdgcn_global_load_lds(
      (const __attribute__((address_space(1))) void*)g,
      (__attribute__((address_space(3))) void*)l, 16, 0, 0);
}

// ---------------------------------------------------------------------------
// fp32 -> bf16 conversion of x and the 4 weight matrices (one launch)
// ---------------------------------------------------------------------------
__global__ __launch_bounds__(256) void cvt_all(
    const float* __restrict__ x,  const float* __restrict__ wq,
    const float* __restrict__ wk, const float* __restrict__ wv,
    const float* __restrict__ wo,
    ushort* __restrict__ xb,  ushort* __restrict__ wqb, ushort* __restrict__ wkb,
    ushort* __restrict__ wvb, ushort* __restrict__ wob)
{
  size_t e = ((size_t)blockIdx.x * 256 + threadIdx.x) * 4;
  const float* s; ushort* d; size_t off;
  if      (e < 4194304) { s = x;  d = xb;  off = e; }
  else if (e < 5242880) { s = wq; d = wqb; off = e - 4194304; }
  else if (e < 6291456) { s = wk; d = wkb; off = e - 5242880; }
  else if (e < 7340032) { s = wv; d = wvb; off = e - 6291456; }
  else                  { s = wo; d = wob; off = e - 7340032; }
  float4 f = *(const float4*)(s + off);
  ushort4 o4 = { f2b(f.x), f2b(f.y), f2b(f.z), f2b(f.w) };
  *(ushort4*)(d + off) = o4;
}

// ---------------------------------------------------------------------------
// QKV projection: out[m][n] = sum_k X[m][k] * W[n][k], bf16 MFMA 16x16x32.
// 128x128 tile, BK=64, 4 waves (each 64x64). XOR-swizzled LDS via
// pre-swizzled global source for global_load_lds.
// Epilogue: RoPE (z=0,1), Q pre-scaled by 0.125, V written transposed
// [b][h][d][s]. Outputs bf16.
// ---------------------------------------------------------------------------
__global__ __launch_bounds__(256) void gemm_qkv(
    const ushort* __restrict__ X,
    const ushort* __restrict__ Wq, const ushort* __restrict__ Wk, const ushort* __restrict__ Wv,
    ushort* __restrict__ Q, ushort* __restrict__ K, ushort* __restrict__ Vt,
    const int* __restrict__ pos)
{
  __shared__ __align__(16) char smem[32768];
  char* As = smem;
  char* Bs = smem + 16384;

  const int z = blockIdx.z;
  const ushort* W = (z == 0) ? Wq : (z == 1) ? Wk : Wv;

  const int n0 = blockIdx.x * 128;
  const int m0 = blockIdx.y * 128;
  const int tid  = threadIdx.x;
  const int lane = tid & 63;
  const int w    = tid >> 6;
  const int wm = (w >> 1) * 64;
  const int wn = (w & 1) * 64;
  const int li = lane & 15;
  const int g  = lane >> 4;

  f32x4 acc[4][4] = {};

  for (int k0 = 0; k0 < DM; k0 += 64) {
    __syncthreads();
    #pragma unroll
    for (int it = 0; it < 4; ++it) {
      const int L  = w * 4096 + it * 1024 + lane * 16;
      const int r  = L >> 7;
      const int sc = ((L >> 4) & 7) ^ (r & 7);
      gll16(X + (size_t)(m0 + r) * DM + k0 + sc * 8, As + w * 4096 + it * 1024);
      gll16(W + (size_t)(n0 + r) * DM + k0 + sc * 8, Bs + w * 4096 + it * 1024);
    }
    __syncthreads();

    #pragma unroll
    for (int ks = 0; ks < 2; ++ks) {
      bf16x8 af[4], bfr[4];
      #pragma unroll
      for (int mf = 0; mf < 4; ++mf) {
        const int row = wm + mf * 16 + li;
        af[mf] = *(const bf16x8*)(As + row * 128 + (((ks * 4 + g) ^ (row & 7)) << 4));
      }
      #pragma unroll
      for (int nf = 0; nf < 4; ++nf) {
        const int row = wn + nf * 16 + li;
        bfr[nf] = *(const bf16x8*)(Bs + row * 128 + (((ks * 4 + g) ^ (row & 7)) << 4));
      }
      #pragma unroll
      for (int mf = 0; mf < 4; ++mf)
        #pragma unroll
        for (int nf = 0; nf < 4; ++nf)
          acc[mf][nf] = __builtin_amdgcn_mfma_f32_16x16x32_bf16(af[mf], bfr[nf], acc[mf][nf], 0, 0, 0);
    }
  }

  #pragma unroll
  for (int nf = 0; nf < 4; ++nf) {
    const int n = n0 + wn + nf * 16 + li;   // output channel
    const int h = n >> 6;
    const int d = n & 63;
    if (z == 2) {
      // V: pack 4 consecutive s, write transposed [b][h][d][s]
      #pragma unroll
      for (int mf = 0; mf < 4; ++mf) {
        const int m  = m0 + wm + mf * 16 + g * 4;
        const int b  = m >> 11;
        const int s2 = m & (SEQ - 1);
        ushort4 pk = { f2b(acc[mf][nf][0]), f2b(acc[mf][nf][1]),
                       f2b(acc[mf][nf][2]), f2b(acc[mf][nf][3]) };
        *(ushort4*)(Vt + (((size_t)b * NH + h) * DKH + d) * SEQ + s2) = pk;
      }
    } else {
      ushort* DST = (z == 0) ? Q : K;
      // freq = 10000^(-(d>>1)/32) = exp(-(d>>1) * ln(10000)/32)
      const float freq = __expf(-(float)(d >> 1) * 0.2878231366242557f);
      #pragma unroll
      for (int mf = 0; mf < 4; ++mf) {
        #pragma unroll
        for (int r = 0; r < 4; ++r) {
          const int m  = m0 + wm + mf * 16 + g * 4 + r;
          const int b  = m >> 11;
          const int s2 = m & (SEQ - 1);
          const float ang = (float)pos[s2] * freq;
          float sn, cs;
          __sincosf(ang, &sn, &cs);
          const float v1 = acc[mf][nf][r];
          const float v2 = __shfl_xor(v1, 1);     // partner dim (d^1), same layout
          float ov = (d & 1) ? (v2 * sn + v1 * cs)    // r2 = x1*sin + x2*cos
                             : (v1 * cs - v2 * sn);   // r1 = x1*cos - x2*sin
          if (z == 0) ov *= 0.125f;               // fold 1/sqrt(dk) into Q
          DST[(((size_t)b * NH + h) * SEQ + s2) * DKH + d] = f2b(ov);
        }
      }
    }
  }
}

// ---------------------------------------------------------------------------
// Wo projection: fp32 output, same GEMM core.
// ---------------------------------------------------------------------------
__global__ __launch_bounds__(256) void gemm_wo(
    const ushort* __restrict__ A, const ushort* __restrict__ W,
    float* __restrict__ out)
{
  __shared__ __align__(16) char smem[32768];
  char* As = smem;
  char* Bs = smem + 16384;

  const int n0 = blockIdx.x * 128;
  const int m0 = blockIdx.y * 128;
  const int tid  = threadIdx.x;
  const int lane = tid & 63;
  const int w    = tid >> 6;
  const int wm = (w >> 1) * 64;
  const int wn = (w & 1) * 64;
  const int li = lane & 15;
  const int g  = lane >> 4;

  f32x4 acc[4][4] = {};

  for (int k0 = 0; k0 < DM; k0 += 64) {
    __syncthreads();
    #pragma unroll
    for (int it = 0; it < 4; ++it) {
      const int L  = w * 4096 + it * 1024 + lane * 16;
      const int r  = L >> 7;
      const int sc = ((L >> 4) & 7) ^ (r & 7);
      gll16(A + (size_t)(m0 + r) * DM + k0 + sc * 8, As + w * 4096 + it * 1024);
      gll16(W + (size_t)(n0 + r) * DM + k0 + sc * 8, Bs + w * 4096 + it * 1024);
    }
    __syncthreads();

    #pragma unroll
    for (int ks = 0; ks < 2; ++ks) {
      bf16x8 af[4], bfr[4];
      #pragma unroll
      for (int mf = 0; mf < 4; ++mf) {
        const int row = wm + mf * 16 + li;
        af[mf] = *(const bf16x8*)(As + row * 128 + (((ks * 4 + g) ^ (row & 7)) << 4));
      }
      #pragma unroll
      for (int nf = 0; nf < 4; ++nf) {
        const int row = wn + nf * 16 + li;
        bfr[nf] = *(const bf16x8*)(Bs + row * 128 + (((ks * 4 + g) ^ (row & 7)) << 4));
      }
      #pragma unroll
      for (int mf = 0; mf < 4; ++mf)
        #pragma unroll
        for (int nf = 0; nf < 4; ++nf)
          acc[mf][nf] = __builtin_amdgcn_mfma_f32_16x16x32_bf16(af[mf], bfr[nf], acc[mf][nf], 0, 0, 0);
    }
  }

  #pragma unroll
  for (int nf = 0; nf < 4; ++nf)
    #pragma unroll
    for (int mf = 0; mf < 4; ++mf)
      #pragma unroll
      for (int r = 0; r < 4; ++r)
        out[(size_t)(m0 + wm + mf * 16 + g * 4 + r) * DM + n0 + wn + nf * 16 + li] = acc[mf][nf][r];
}

// ---------------------------------------------------------------------------
// Causal flash attention, bf16 MFMA.
// Q,K: [b][h][s][64] bf16 (Q pre-scaled 0.125). Vt: [b][h][64][s] bf16.
// Block = (b,h) x 64-query tile; 4 waves, wave w owns q-rows [w*16, w*16+16).
// K/V tiles in swizzled LDS via global_load_lds; P through wave-private
// swizzled LDS rows. Output AO: [b][s][h*64+d] bf16.
// ---------------------------------------------------------------------------
__global__ __launch_bounds__(256) void attn(
    const ushort* __restrict__ Q, const ushort* __restrict__ K,
    const ushort* __restrict__ Vt, ushort* __restrict__ AO)
{
  __shared__ __align__(16) char smem[24576];
  char* Ks = smem;
  char* Vs = smem + 8192;
  char* Ps = smem + 16384;

  const int bh = blockIdx.y;
  const int qt = blockIdx.x;
  const int q0 = qt * 64;
  const ushort* Qb = Q  + (size_t)bh * SEQ * DKH;
  const ushort* Kb = K  + (size_t)bh * SEQ * DKH;
  const ushort* Vb = Vt + (size_t)bh * DKH * SEQ;

  const int tid  = threadIdx.x;
  const int lane = tid & 63;
  const int w    = tid >> 6;
  const int li   = lane & 15;
  const int g    = lane >> 4;

  // Q a-frags for this wave's 16 q-rows (held in regs across the kv loop)
  bf16x8 qf[2];
  {
    const int qrow = q0 + w * 16 + li;
    qf[0] = *(const bf16x8*)(Qb + (size_t)qrow * DKH + g * 8);
    qf[1] = *(const bf16x8*)(Qb + (size_t)qrow * DKH + 32 + g * 8);
  }

  f32x4 o[4] = {};
  float m_[4], l_[4];
  #pragma unroll
  for (int r = 0; r < 4; ++r) { m_[r] = -INFINITY; l_[r] = 0.f; }

  for (int kt = 0; kt <= qt; ++kt) {
    const int k0 = kt * 64;
    __syncthreads();                       // all waves done with prev K/V
    #pragma unroll
    for (int it = 0; it < 2; ++it) {
      const int L  = w * 2048 + it * 1024 + lane * 16;
      const int r  = L >> 7;
      const int sc = ((L >> 4) & 7) ^ (r & 7);
      gll16(Kb + (size_t)(k0 + r) * DKH + sc * 8, Ks + w * 2048 + it * 1024);
      gll16(Vb + (size_t)r * SEQ + k0 + sc * 8,   Vs + w * 2048 + it * 1024);
    }
    __syncthreads();                       // staging complete (barrier drains vmcnt)

    // S = Q K^T : 16 q-rows x 64 kv
    f32x4 sf[4] = {};
    #pragma unroll
    for (int nf = 0; nf < 4; ++nf) {
      #pragma unroll
      for (int ks = 0; ks < 2; ++ks) {
        const int row = nf * 16 + li;
        bf16x8 kf = *(const bf16x8*)(Ks + row * 128 + (((ks * 4 + g) ^ (row & 7)) << 4));
        sf[nf] = __builtin_amdgcn_mfma_f32_16x16x32_bf16(qf[ks], kf, sf[nf], 0, 0, 0);
      }
    }

    if (kt == qt) {                        // causal mask on the diagonal tile
      #pragma unroll
      for (int nf = 0; nf < 4; ++nf)
        #pragma unroll
        for (int r = 0; r < 4; ++r)
          if (k0 + nf * 16 + li > q0 + w * 16 + g * 4 + r) sf[nf][r] = -1e30f;
    }

    // online softmax (row q = w*16 + g*4 + r; reduce over nf in-lane + 16 lanes)
    #pragma unroll
    for (int r = 0; r < 4; ++r) {
      float mx = fmaxf(fmaxf(sf[0][r], sf[1][r]), fmaxf(sf[2][r], sf[3][r]));
      #pragma unroll
      for (int off = 1; off < 16; off <<= 1) mx = fmaxf(mx, __shfl_xor(mx, off));
      const float newm = fmaxf(m_[r], mx);
      const float al   = __expf(m_[r] - newm);
      float rs = 0.f;
      #pragma unroll
      for (int nf = 0; nf < 4; ++nf) { sf[nf][r] = __expf(sf[nf][r] - newm); rs += sf[nf][r]; }
      #pragma unroll
      for (int off = 1; off < 16; off <<= 1) rs += __shfl_xor(rs, off);
      l_[r] = l_[r] * al + rs;
      m_[r] = newm;
      #pragma unroll
      for (int nf = 0; nf < 4; ++nf) o[nf][r] *= al;
    }

    // P -> wave-private LDS rows (swizzled), then read back as a-frags
    #pragma unroll
    for (int nf = 0; nf < 4; ++nf) {
      #pragma unroll
      for (int r = 0; r < 4; ++r) {
        const int prow = w * 16 + g * 4 + r;
        const int cb   = (nf * 16 + li) * 2;
        *(ushort*)(Ps + prow * 128 + (cb ^ ((prow & 7) << 4))) = f2b(sf[nf][r]);
      }
    }
    bf16x8 pf[2];
    {
      const int prow = w * 16 + li;
      pf[0] = *(const bf16x8*)(Ps + prow * 128 + (((g    ) ^ (prow & 7)) << 4));
      pf[1] = *(const bf16x8*)(Ps + prow * 128 + (((4 + g) ^ (prow & 7)) << 4));
    }

    // O += P V  (B-frags contiguous thanks to transposed V)
    #pragma unroll
    for (int nf = 0; nf < 4; ++nf) {
      #pragma unroll
      for (int ks = 0; ks < 2; ++ks) {
        const int row = nf * 16 + li;
        bf16x8 vf = *(const bf16x8*)(Vs + row * 128 + (((ks * 4 + g) ^ (row & 7)) << 4));
        o[nf] = __builtin_amdgcn_mfma_f32_16x16x32_bf16(pf[ks], vf, o[nf], 0, 0, 0);
      }
    }
  }

  const int b = bh >> 4, h = bh & 15;
  #pragma unroll
  for (int nf = 0; nf < 4; ++nf) {
    #pragma unroll
    for (int r = 0; r < 4; ++r) {
      const int q = q0 + w * 16 + g * 4 + r;
      AO[((size_t)b * SEQ + q) * DM + h * DKH + nf * 16 + li] = f2b(o[nf][r] / l_[r]);
    }
  }
}

// ---------------------------------------------------------------------------
extern "C" void kernel_launch(void* const* d_in, const int* in_sizes, int n_in,
                              void* d_out, int out_size, void* d_ws, size_t ws_size,
                              hipStream_t stream)
{
  const float* x   = (const float*)d_in[0];
  const int*   pos = (const int*)  d_in[1];
  const float* Wq  = (const float*)d_in[2];
  const float* Wk  = (const float*)d_in[3];
  const float* Wv  = (const float*)d_in[4];
  const float* Wo  = (const float*)d_in[5];
  float* out = (float*)d_out;

  ushort* ws  = (ushort*)d_ws;
  ushort* xb  = ws;                    // 4M
  ushort* wqb = xb  + 4194304;         // 1M each
  ushort* wkb = wqb + 1048576;
  ushort* wvb = wkb + 1048576;
  ushort* wob = wvb + 1048576;
  ushort* Qb  = wob + 1048576;         // 4M each
  ushort* Kb  = Qb  + 4194304;
  ushort* Vtb = Kb  + 4194304;
  ushort* AOb = Vtb + 4194304;

  cvt_all<<<8192, 256, 0, stream>>>(x, Wq, Wk, Wv, Wo, xb, wqb, wkb, wvb, wob);
  gemm_qkv<<<dim3(8, 32, 3), 256, 0, stream>>>(xb, wqb, wkb, wvb, Qb, Kb, Vtb, pos);
  attn<<<dim3(32, 32), 256, 0, stream>>>(Qb, Kb, Vtb, AOb);
  gemm_wo<<<dim3(8, 32), 256, 0, stream>>>(AOb, wob, out);
}

// Round 3
// 209.249 us; speedup vs baseline: 6.8554x; 1.0422x over previous
//
#include <hip/hip_runtime.h>
#include <math.h>

#define SEQ 2048
#define NH  16
#define DKH 64
#define DM  1024
#define MR  4096   // BATCH*SEQ

using bf16x8 = __attribute__((ext_vector_type(8))) short;
using f32x4  = __attribute__((ext_vector_type(4))) float;

__device__ __forceinline__ ushort f2b(float f) {
  unsigned u = __float_as_uint(f);
  return (ushort)((u + 0x7fffu + ((u >> 16) & 1u)) >> 16);
}

__device__ __forceinline__ void gll16(const void* g, void* l) {
  __builtin_amdgcn_global_load_lds(
      (const __attribute__((address_space(1))) void*)g,
      (__attribute__((address_space(3))) void*)l, 16, 0, 0);
}

// ---------------------------------------------------------------------------
// fp32 -> bf16 conversion of x and the 4 weight matrices (one launch)
// ---------------------------------------------------------------------------
__global__ __launch_bounds__(256) void cvt_all(
    const float* __restrict__ x,  const float* __restrict__ wq,
    const float* __restrict__ wk, const float* __restrict__ wv,
    const float* __restrict__ wo,
    ushort* __restrict__ xb,  ushort* __restrict__ wqb, ushort* __restrict__ wkb,
    ushort* __restrict__ wvb, ushort* __restrict__ wob)
{
  size_t e = ((size_t)blockIdx.x * 256 + threadIdx.x) * 4;
  const float* s; ushort* d; size_t off;
  if      (e < 4194304) { s = x;  d = xb;  off = e; }
  else if (e < 5242880) { s = wq; d = wqb; off = e - 4194304; }
  else if (e < 6291456) { s = wk; d = wkb; off = e - 5242880; }
  else if (e < 7340032) { s = wv; d = wvb; off = e - 6291456; }
  else                  { s = wo; d = wob; off = e - 7340032; }
  float4 f = *(const float4*)(s + off);
  ushort4 o4 = { f2b(f.x), f2b(f.y), f2b(f.z), f2b(f.w) };
  *(ushort4*)(d + off) = o4;
}

// ---------------------------------------------------------------------------
// QKV projection: out[m][n] = sum_k X[m][k] * W[n][k], bf16 MFMA 16x16x32.
// 128x128 tile, BK=64, 4 waves. Epilogue: RoPE (z=0,1), Q pre-scaled 0.125,
// V written transposed [b][h][d][s]. Outputs bf16.
// ---------------------------------------------------------------------------
__global__ __launch_bounds__(256) void gemm_qkv(
    const ushort* __restrict__ X,
    const ushort* __restrict__ Wq, const ushort* __restrict__ Wk, const ushort* __restrict__ Wv,
    ushort* __restrict__ Q, ushort* __restrict__ K, ushort* __restrict__ Vt,
    const int* __restrict__ pos)
{
  __shared__ __align__(16) char smem[32768];
  char* As = smem;
  char* Bs = smem + 16384;

  const int z = blockIdx.z;
  const ushort* W = (z == 0) ? Wq : (z == 1) ? Wk : Wv;

  const int n0 = blockIdx.x * 128;
  const int m0 = blockIdx.y * 128;
  const int tid  = threadIdx.x;
  const int lane = tid & 63;
  const int w    = tid >> 6;
  const int wm = (w >> 1) * 64;
  const int wn = (w & 1) * 64;
  const int li = lane & 15;
  const int g  = lane >> 4;

  f32x4 acc[4][4] = {};

  for (int k0 = 0; k0 < DM; k0 += 64) {
    __syncthreads();
    #pragma unroll
    for (int it = 0; it < 4; ++it) {
      const int L  = w * 4096 + it * 1024 + lane * 16;
      const int r  = L >> 7;
      const int sc = ((L >> 4) & 7) ^ (r & 7);
      gll16(X + (size_t)(m0 + r) * DM + k0 + sc * 8, As + w * 4096 + it * 1024);
      gll16(W + (size_t)(n0 + r) * DM + k0 + sc * 8, Bs + w * 4096 + it * 1024);
    }
    __syncthreads();

    #pragma unroll
    for (int ks = 0; ks < 2; ++ks) {
      bf16x8 af[4], bfr[4];
      #pragma unroll
      for (int mf = 0; mf < 4; ++mf) {
        const int row = wm + mf * 16 + li;
        af[mf] = *(const bf16x8*)(As + row * 128 + (((ks * 4 + g) ^ (row & 7)) << 4));
      }
      #pragma unroll
      for (int nf = 0; nf < 4; ++nf) {
        const int row = wn + nf * 16 + li;
        bfr[nf] = *(const bf16x8*)(Bs + row * 128 + (((ks * 4 + g) ^ (row & 7)) << 4));
      }
      #pragma unroll
      for (int mf = 0; mf < 4; ++mf)
        #pragma unroll
        for (int nf = 0; nf < 4; ++nf)
          acc[mf][nf] = __builtin_amdgcn_mfma_f32_16x16x32_bf16(af[mf], bfr[nf], acc[mf][nf], 0, 0, 0);
    }
  }

  #pragma unroll
  for (int nf = 0; nf < 4; ++nf) {
    const int n = n0 + wn + nf * 16 + li;   // output channel
    const int h = n >> 6;
    const int d = n & 63;
    if (z == 2) {
      #pragma unroll
      for (int mf = 0; mf < 4; ++mf) {
        const int m  = m0 + wm + mf * 16 + g * 4;
        const int b  = m >> 11;
        const int s2 = m & (SEQ - 1);
        ushort4 pk = { f2b(acc[mf][nf][0]), f2b(acc[mf][nf][1]),
                       f2b(acc[mf][nf][2]), f2b(acc[mf][nf][3]) };
        *(ushort4*)(Vt + (((size_t)b * NH + h) * DKH + d) * SEQ + s2) = pk;
      }
    } else {
      ushort* DST = (z == 0) ? Q : K;
      const float freq = __expf(-(float)(d >> 1) * 0.2878231366242557f);
      #pragma unroll
      for (int mf = 0; mf < 4; ++mf) {
        #pragma unroll
        for (int r = 0; r < 4; ++r) {
          const int m  = m0 + wm + mf * 16 + g * 4 + r;
          const int b  = m >> 11;
          const int s2 = m & (SEQ - 1);
          const float ang = (float)pos[s2] * freq;
          float sn, cs;
          __sincosf(ang, &sn, &cs);
          const float v1 = acc[mf][nf][r];
          const float v2 = __shfl_xor(v1, 1);
          float ov = (d & 1) ? (v2 * sn + v1 * cs)
                             : (v1 * cs - v2 * sn);
          if (z == 0) ov *= 0.125f;
          DST[(((size_t)b * NH + h) * SEQ + s2) * DKH + d] = f2b(ov);
        }
      }
    }
  }
}

// ---------------------------------------------------------------------------
// Wo projection: fp32 output, same GEMM core.
// ---------------------------------------------------------------------------
__global__ __launch_bounds__(256) void gemm_wo(
    const ushort* __restrict__ A, const ushort* __restrict__ W,
    float* __restrict__ out)
{
  __shared__ __align__(16) char smem[32768];
  char* As = smem;
  char* Bs = smem + 16384;

  const int n0 = blockIdx.x * 128;
  const int m0 = blockIdx.y * 128;
  const int tid  = threadIdx.x;
  const int lane = tid & 63;
  const int w    = tid >> 6;
  const int wm = (w >> 1) * 64;
  const int wn = (w & 1) * 64;
  const int li = lane & 15;
  const int g  = lane >> 4;

  f32x4 acc[4][4] = {};

  for (int k0 = 0; k0 < DM; k0 += 64) {
    __syncthreads();
    #pragma unroll
    for (int it = 0; it < 4; ++it) {
      const int L  = w * 4096 + it * 1024 + lane * 16;
      const int r  = L >> 7;
      const int sc = ((L >> 4) & 7) ^ (r & 7);
      gll16(A + (size_t)(m0 + r) * DM + k0 + sc * 8, As + w * 4096 + it * 1024);
      gll16(W + (size_t)(n0 + r) * DM + k0 + sc * 8, Bs + w * 4096 + it * 1024);
    }
    __syncthreads();

    #pragma unroll
    for (int ks = 0; ks < 2; ++ks) {
      bf16x8 af[4], bfr[4];
      #pragma unroll
      for (int mf = 0; mf < 4; ++mf) {
        const int row = wm + mf * 16 + li;
        af[mf] = *(const bf16x8*)(As + row * 128 + (((ks * 4 + g) ^ (row & 7)) << 4));
      }
      #pragma unroll
      for (int nf = 0; nf < 4; ++nf) {
        const int row = wn + nf * 16 + li;
        bfr[nf] = *(const bf16x8*)(Bs + row * 128 + (((ks * 4 + g) ^ (row & 7)) << 4));
      }
      #pragma unroll
      for (int mf = 0; mf < 4; ++mf)
        #pragma unroll
        for (int nf = 0; nf < 4; ++nf)
          acc[mf][nf] = __builtin_amdgcn_mfma_f32_16x16x32_bf16(af[mf], bfr[nf], acc[mf][nf], 0, 0, 0);
    }
  }

  #pragma unroll
  for (int nf = 0; nf < 4; ++nf)
    #pragma unroll
    for (int mf = 0; mf < 4; ++mf)
      #pragma unroll
      for (int r = 0; r < 4; ++r)
        out[(size_t)(m0 + wm + mf * 16 + g * 4 + r) * DM + n0 + wn + nf * 16 + li] = acc[mf][nf][r];
}

// ---------------------------------------------------------------------------
// Causal flash attention, bf16 MFMA, barrier-free.
// Q,K: [b][h][s][64] bf16 (Q pre-scaled 0.125). Vt: [b][h][64][s] bf16.
// One wave = one 16-row q-tile. Block = 4 waves, same (b,h), same kv trip
// count (uniform work). K/V read directly from global (L2-resident) into
// MFMA fragments. Swapped QK^T (mfma(K,Q)) -> lane-local softmax rows.
// P transposed through wave-private swizzled LDS (no barriers anywhere).
// Heavy blocks dispatched first; heads pinned to XCDs via blockIdx&7.
// ---------------------------------------------------------------------------
__global__ __launch_bounds__(256) void attn(
    const ushort* __restrict__ Q, const ushort* __restrict__ K,
    const ushort* __restrict__ Vt, ushort* __restrict__ AO)
{
  __shared__ __align__(16) char Ps[8192];   // 4 waves x 16 x 128B (swizzled)

  const int tid  = threadIdx.x;
  const int lane = tid & 63;
  const int w    = tid >> 6;
  const int li   = lane & 15;
  const int g    = lane >> 4;

  const int bx  = blockIdx.x;          // 1024 blocks
  const int xcd = bx & 7;
  const int j   = bx >> 3;             // 0..127
  const int bh  = (j & 3) * 8 + xcd;   // same-bh blocks share an XCD slot
  const int qg  = 31 - (j >> 2);       // heavy (long) blocks first
  const int qtile = qg * 4 + w;        // wave's 16-row q tile
  const int q0  = qtile * 16;
  const int nkt = qg + 1;              // 64-kv tiles (uniform across block)

  const ushort* Qb = Q  + (size_t)bh * SEQ * DKH;
  const ushort* Kb = K  + (size_t)bh * SEQ * DKH;
  const ushort* Vb = Vt + (size_t)bh * DKH * SEQ;
  char* Pw = Ps + w * 2048;

  // Q fragments (B-role): lane holds Q[q0+li][d = ks*32 + g*8 .. +8]
  bf16x8 qf[2];
  qf[0] = *(const bf16x8*)(Qb + (size_t)(q0 + li) * DKH + g * 8);
  qf[1] = *(const bf16x8*)(Qb + (size_t)(q0 + li) * DKH + 32 + g * 8);

  f32x4 o[4] = {};
  float m_ = -INFINITY, l_ = 0.f;

  for (int kt = 0; kt < nkt; ++kt) {
    const int k0 = kt * 64;
    const bool last = (kt == nkt - 1);

    // K fragments (A-role): lane holds K[k0+nf*16+li][d = ks*32+g*8..]
    bf16x8 kf0[4], kf1[4];
    #pragma unroll
    for (int nf = 0; nf < 4; ++nf) {
      const ushort* kr = Kb + (size_t)(k0 + nf * 16 + li) * DKH + g * 8;
      kf0[nf] = *(const bf16x8*)(kr);
      kf1[nf] = *(const bf16x8*)(kr + 32);
    }

    // S^T = K Q^T : st[nf][r] = S[q = q0+li][k = k0 + nf*16 + g*4 + r]
    f32x4 st[4] = {};
    #pragma unroll
    for (int nf = 0; nf < 4; ++nf) {
      st[nf] = __builtin_amdgcn_mfma_f32_16x16x32_bf16(kf0[nf], qf[0], st[nf], 0, 0, 0);
      st[nf] = __builtin_amdgcn_mfma_f32_16x16x32_bf16(kf1[nf], qf[1], st[nf], 0, 0, 0);
    }

    // V fragments (B-role): lane holds V[k = ks*32+g*8..][d = nf*16+li]
    // (issued here so their latency hides under the softmax VALU work)
    bf16x8 vf0[4], vf1[4];
    #pragma unroll
    for (int nf = 0; nf < 4; ++nf) {
      const ushort* vr = Vb + (size_t)(nf * 16 + li) * SEQ + k0 + g * 8;
      vf0[nf] = *(const bf16x8*)(vr);
      vf1[nf] = *(const bf16x8*)(vr + 32);
    }

    if (last) {                        // causal mask (diagonal tile)
      #pragma unroll
      for (int nf = 0; nf < 4; ++nf)
        #pragma unroll
        for (int r = 0; r < 4; ++r)
          if (k0 + nf * 16 + g * 4 + r > q0 + li) st[nf][r] = -1e30f;
    }

    // lane-local online softmax for q = q0 + li (16 kv values per lane)
    float mx = fmaxf(fmaxf(fmaxf(st[0][0], st[0][1]), fmaxf(st[0][2], st[0][3])),
                     fmaxf(fmaxf(st[1][0], st[1][1]), fmaxf(st[1][2], st[1][3])));
    mx = fmaxf(mx, fmaxf(fmaxf(fmaxf(st[2][0], st[2][1]), fmaxf(st[2][2], st[2][3])),
                         fmaxf(fmaxf(st[3][0], st[3][1]), fmaxf(st[3][2], st[3][3]))));
    mx = fmaxf(mx, __shfl_xor(mx, 16));
    mx = fmaxf(mx, __shfl_xor(mx, 32));
    const float newm = fmaxf(m_, mx);
    const float al = __expf(m_ - newm);
    m_ = newm;

    float p[4][4];
    float rs = 0.f;
    #pragma unroll
    for (int nf = 0; nf < 4; ++nf)
      #pragma unroll
      for (int r = 0; r < 4; ++r) {
        p[nf][r] = __expf(st[nf][r] - newm);
        rs += p[nf][r];
      }
    rs += __shfl_xor(rs, 16);
    rs += __shfl_xor(rs, 32);
    l_ = l_ * al + rs;

    // rescale O (rows q = g*4 + r need al from lane li = g*4 + r)
    float alr[4];
    #pragma unroll
    for (int r = 0; r < 4; ++r) alr[r] = __shfl(al, g * 4 + r);
    #pragma unroll
    for (int nf = 0; nf < 4; ++nf)
      #pragma unroll
      for (int r = 0; r < 4; ++r) o[nf][r] *= alr[r];

    // P -> wave-private LDS (transpose to A-frag layout), XOR-swizzled 16B chunks
    #pragma unroll
    for (int nf = 0; nf < 4; ++nf) {
      ushort4 pk = { f2b(p[nf][0]), f2b(p[nf][1]), f2b(p[nf][2]), f2b(p[nf][3]) };
      const int cw = nf * 2 + (g >> 1);          // 16B chunk within row
      *(ushort4*)(Pw + li * 128 + ((cw ^ (li & 7)) << 4) + ((g & 1) << 3)) = pk;
    }
    bf16x8 pf[2];
    pf[0] = *(const bf16x8*)(Pw + li * 128 + (((0 * 4 + g) ^ (li & 7)) << 4));
    pf[1] = *(const bf16x8*)(Pw + li * 128 + (((1 * 4 + g) ^ (li & 7)) << 4));

    // O += P V
    #pragma unroll
    for (int nf = 0; nf < 4; ++nf) {
      o[nf] = __builtin_amdgcn_mfma_f32_16x16x32_bf16(pf[0], vf0[nf], o[nf], 0, 0, 0);
      o[nf] = __builtin_amdgcn_mfma_f32_16x16x32_bf16(pf[1], vf1[nf], o[nf], 0, 0, 0);
    }
  }

  // finalize: rows q = g*4+r need 1/l from lane li = g*4+r
  const float inv = 1.0f / l_;
  float invr[4];
  #pragma unroll
  for (int r = 0; r < 4; ++r) invr[r] = __shfl(inv, g * 4 + r);

  const int b = bh >> 4, h = bh & 15;
  #pragma unroll
  for (int nf = 0; nf < 4; ++nf)
    #pragma unroll
    for (int r = 0; r < 4; ++r) {
      const int q = q0 + g * 4 + r;
      AO[((size_t)b * SEQ + q) * DM + h * DKH + nf * 16 + li] = f2b(o[nf][r] * invr[r]);
    }
}

// ---------------------------------------------------------------------------
extern "C" void kernel_launch(void* const* d_in, const int* in_sizes, int n_in,
                              void* d_out, int out_size, void* d_ws, size_t ws_size,
                              hipStream_t stream)
{
  const float* x   = (const float*)d_in[0];
  const int*   pos = (const int*)  d_in[1];
  const float* Wq  = (const float*)d_in[2];
  const float* Wk  = (const float*)d_in[3];
  const float* Wv  = (const float*)d_in[4];
  const float* Wo  = (const float*)d_in[5];
  float* out = (float*)d_out;

  ushort* ws  = (ushort*)d_ws;
  ushort* xb  = ws;                    // 4M
  ushort* wqb = xb  + 4194304;         // 1M each
  ushort* wkb = wqb + 1048576;
  ushort* wvb = wkb + 1048576;
  ushort* wob = wvb + 1048576;
  ushort* Qb  = wob + 1048576;         // 4M each
  ushort* Kb  = Qb  + 4194304;
  ushort* Vtb = Kb  + 4194304;
  ushort* AOb = Vtb + 4194304;

  cvt_all<<<8192, 256, 0, stream>>>(x, Wq, Wk, Wv, Wo, xb, wqb, wkb, wvb, wob);
  gemm_qkv<<<dim3(8, 32, 3), 256, 0, stream>>>(xb, wqb, wkb, wvb, Qb, Kb, Vtb, pos);
  attn<<<1024, 256, 0, stream>>>(Qb, Kb, Vtb, AOb);
  gemm_wo<<<dim3(8, 32), 256, 0, stream>>>(AOb, wob, out);
}

// Round 4
// 202.857 us; speedup vs baseline: 7.0715x; 1.0315x over previous
//
#include <hip/hip_runtime.h>
#include <math.h>

#define SEQ 2048
#define NH  16
#define DKH 64
#define DM  1024
#define MR  4096   // BATCH*SEQ

using bf16x8 = __attribute__((ext_vector_type(8))) short;
using f32x4  = __attribute__((ext_vector_type(4))) float;

__device__ __forceinline__ ushort f2b(float f) {
  unsigned u = __float_as_uint(f);
  return (ushort)((u + 0x7fffu + ((u >> 16) & 1u)) >> 16);
}

__device__ __forceinline__ void gll16(const void* g, void* l) {
  __builtin_amdgcn_global_load_lds(
      (const __attribute__((address_space(1))) void*)g,
      (__attribute__((address_space(3))) void*)l, 16, 0, 0);
}

// ---------------------------------------------------------------------------
// fp32 -> bf16 conversion of x and the 4 weight matrices (one launch)
// ---------------------------------------------------------------------------
__global__ __launch_bounds__(256) void cvt_all(
    const float* __restrict__ x,  const float* __restrict__ wq,
    const float* __restrict__ wk, const float* __restrict__ wv,
    const float* __restrict__ wo,
    ushort* __restrict__ xb,  ushort* __restrict__ wqb, ushort* __restrict__ wkb,
    ushort* __restrict__ wvb, ushort* __restrict__ wob)
{
  size_t e = ((size_t)blockIdx.x * 256 + threadIdx.x) * 4;
  const float* s; ushort* d; size_t off;
  if      (e < 4194304) { s = x;  d = xb;  off = e; }
  else if (e < 5242880) { s = wq; d = wqb; off = e - 4194304; }
  else if (e < 6291456) { s = wk; d = wkb; off = e - 5242880; }
  else if (e < 7340032) { s = wv; d = wvb; off = e - 6291456; }
  else                  { s = wo; d = wob; off = e - 7340032; }
  float4 f = *(const float4*)(s + off);
  ushort4 o4 = { f2b(f.x), f2b(f.y), f2b(f.z), f2b(f.w) };
  *(ushort4*)(d + off) = o4;
}

// ---------------------------------------------------------------------------
// QKV projection: out[m][n] = sum_k X[m][k] * W[n][k], bf16 MFMA 16x16x32.
// 128x128 tile, BK=64, 4 waves. Epilogue: RoPE (z=0,1), Q pre-scaled 0.125,
// V written transposed [b][h][d][s]. Outputs bf16.
// ---------------------------------------------------------------------------
__global__ __launch_bounds__(256) void gemm_qkv(
    const ushort* __restrict__ X,
    const ushort* __restrict__ Wq, const ushort* __restrict__ Wk, const ushort* __restrict__ Wv,
    ushort* __restrict__ Q, ushort* __restrict__ K, ushort* __restrict__ Vt,
    const int* __restrict__ pos)
{
  __shared__ __align__(16) char smem[32768];
  char* As = smem;
  char* Bs = smem + 16384;

  const int z = blockIdx.z;
  const ushort* W = (z == 0) ? Wq : (z == 1) ? Wk : Wv;

  const int n0 = blockIdx.x * 128;
  const int m0 = blockIdx.y * 128;
  const int tid  = threadIdx.x;
  const int lane = tid & 63;
  const int w    = tid >> 6;
  const int wm = (w >> 1) * 64;
  const int wn = (w & 1) * 64;
  const int li = lane & 15;
  const int g  = lane >> 4;

  f32x4 acc[4][4] = {};

  for (int k0 = 0; k0 < DM; k0 += 64) {
    __syncthreads();
    #pragma unroll
    for (int it = 0; it < 4; ++it) {
      const int L  = w * 4096 + it * 1024 + lane * 16;
      const int r  = L >> 7;
      const int sc = ((L >> 4) & 7) ^ (r & 7);
      gll16(X + (size_t)(m0 + r) * DM + k0 + sc * 8, As + w * 4096 + it * 1024);
      gll16(W + (size_t)(n0 + r) * DM + k0 + sc * 8, Bs + w * 4096 + it * 1024);
    }
    __syncthreads();

    #pragma unroll
    for (int ks = 0; ks < 2; ++ks) {
      bf16x8 af[4], bfr[4];
      #pragma unroll
      for (int mf = 0; mf < 4; ++mf) {
        const int row = wm + mf * 16 + li;
        af[mf] = *(const bf16x8*)(As + row * 128 + (((ks * 4 + g) ^ (row & 7)) << 4));
      }
      #pragma unroll
      for (int nf = 0; nf < 4; ++nf) {
        const int row = wn + nf * 16 + li;
        bfr[nf] = *(const bf16x8*)(Bs + row * 128 + (((ks * 4 + g) ^ (row & 7)) << 4));
      }
      #pragma unroll
      for (int mf = 0; mf < 4; ++mf)
        #pragma unroll
        for (int nf = 0; nf < 4; ++nf)
          acc[mf][nf] = __builtin_amdgcn_mfma_f32_16x16x32_bf16(af[mf], bfr[nf], acc[mf][nf], 0, 0, 0);
    }
  }

  #pragma unroll
  for (int nf = 0; nf < 4; ++nf) {
    const int n = n0 + wn + nf * 16 + li;   // output channel
    const int h = n >> 6;
    const int d = n & 63;
    if (z == 2) {
      #pragma unroll
      for (int mf = 0; mf < 4; ++mf) {
        const int m  = m0 + wm + mf * 16 + g * 4;
        const int b  = m >> 11;
        const int s2 = m & (SEQ - 1);
        ushort4 pk = { f2b(acc[mf][nf][0]), f2b(acc[mf][nf][1]),
                       f2b(acc[mf][nf][2]), f2b(acc[mf][nf][3]) };
        *(ushort4*)(Vt + (((size_t)b * NH + h) * DKH + d) * SEQ + s2) = pk;
      }
    } else {
      ushort* DST = (z == 0) ? Q : K;
      const float freq = __expf(-(float)(d >> 1) * 0.2878231366242557f);
      #pragma unroll
      for (int mf = 0; mf < 4; ++mf) {
        #pragma unroll
        for (int r = 0; r < 4; ++r) {
          const int m  = m0 + wm + mf * 16 + g * 4 + r;
          const int b  = m >> 11;
          const int s2 = m & (SEQ - 1);
          const float ang = (float)pos[s2] * freq;
          float sn, cs;
          __sincosf(ang, &sn, &cs);
          const float v1 = acc[mf][nf][r];
          const float v2 = __shfl_xor(v1, 1);
          float ov = (d & 1) ? (v2 * sn + v1 * cs)
                             : (v1 * cs - v2 * sn);
          if (z == 0) ov *= 0.125f;
          DST[(((size_t)b * NH + h) * SEQ + s2) * DKH + d] = f2b(ov);
        }
      }
    }
  }
}

// ---------------------------------------------------------------------------
// Wo projection: fp32 output, same GEMM core.
// ---------------------------------------------------------------------------
__global__ __launch_bounds__(256) void gemm_wo(
    const ushort* __restrict__ A, const ushort* __restrict__ W,
    float* __restrict__ out)
{
  __shared__ __align__(16) char smem[32768];
  char* As = smem;
  char* Bs = smem + 16384;

  const int n0 = blockIdx.x * 128;
  const int m0 = blockIdx.y * 128;
  const int tid  = threadIdx.x;
  const int lane = tid & 63;
  const int w    = tid >> 6;
  const int wm = (w >> 1) * 64;
  const int wn = (w & 1) * 64;
  const int li = lane & 15;
  const int g  = lane >> 4;

  f32x4 acc[4][4] = {};

  for (int k0 = 0; k0 < DM; k0 += 64) {
    __syncthreads();
    #pragma unroll
    for (int it = 0; it < 4; ++it) {
      const int L  = w * 4096 + it * 1024 + lane * 16;
      const int r  = L >> 7;
      const int sc = ((L >> 4) & 7) ^ (r & 7);
      gll16(A + (size_t)(m0 + r) * DM + k0 + sc * 8, As + w * 4096 + it * 1024);
      gll16(W + (size_t)(n0 + r) * DM + k0 + sc * 8, Bs + w * 4096 + it * 1024);
    }
    __syncthreads();

    #pragma unroll
    for (int ks = 0; ks < 2; ++ks) {
      bf16x8 af[4], bfr[4];
      #pragma unroll
      for (int mf = 0; mf < 4; ++mf) {
        const int row = wm + mf * 16 + li;
        af[mf] = *(const bf16x8*)(As + row * 128 + (((ks * 4 + g) ^ (row & 7)) << 4));
      }
      #pragma unroll
      for (int nf = 0; nf < 4; ++nf) {
        const int row = wn + nf * 16 + li;
        bfr[nf] = *(const bf16x8*)(Bs + row * 128 + (((ks * 4 + g) ^ (row & 7)) << 4));
      }
      #pragma unroll
      for (int mf = 0; mf < 4; ++mf)
        #pragma unroll
        for (int nf = 0; nf < 4; ++nf)
          acc[mf][nf] = __builtin_amdgcn_mfma_f32_16x16x32_bf16(af[mf], bfr[nf], acc[mf][nf], 0, 0, 0);
    }
  }

  #pragma unroll
  for (int nf = 0; nf < 4; ++nf)
    #pragma unroll
    for (int mf = 0; mf < 4; ++mf)
      #pragma unroll
      for (int r = 0; r < 4; ++r)
        out[(size_t)(m0 + wm + mf * 16 + g * 4 + r) * DM + n0 + wn + nf * 16 + li] = acc[mf][nf][r];
}

// ---------------------------------------------------------------------------
// Causal flash attention, bf16 MFMA, split-KV x2 + register-double-buffered
// K/V prefetch, barrier-free main loop.
// Q,K: [b][h][s][64] bf16 (Q pre-scaled 0.125). Vt: [b][h][64][s] bf16.
// One 16-row q-tile = 2 waves (low/high kv halves), merged via LDS at end.
// Block = 4 waves = 2 q-tiles of the same (b,h). Swapped QK^T (mfma(K,Q))
// -> lane-local softmax rows. P transposed through wave-private LDS.
// Heavy blocks dispatched first; heads pinned to XCDs via blockIdx&7.
// ---------------------------------------------------------------------------
__global__ __launch_bounds__(256) void attn(
    const ushort* __restrict__ Q, const ushort* __restrict__ K,
    const ushort* __restrict__ Vt, ushort* __restrict__ AO)
{
  __shared__ __align__(16) char Ps[8192];          // 4 waves x 2KB P-transpose
  __shared__ __align__(16) float OmB[2][64][16];   // B-half partial O
  __shared__ float mlB[2][64][2];                  // B-half (m, l)

  const int tid  = threadIdx.x;
  const int lane = tid & 63;
  const int w    = tid >> 6;
  const int li   = lane & 15;
  const int g    = lane >> 4;
  const int pair = w >> 1;             // which q-tile within block
  const int half = w & 1;              // 0 = low kv half (merger), 1 = high

  const int bx  = blockIdx.x;          // 2048 blocks
  const int xcd = bx & 7;
  const int j   = bx >> 3;             // 0..255
  const int bh  = (j & 3) * 8 + xcd;
  const int u   = 63 - (j >> 2);       // 0..63, heavy (long) first
  const int qtile = u * 2 + pair;      // 0..127
  const int q0  = qtile * 16;
  const int n   = (q0 + 16 + 63) >> 6; // kv tiles of 64 covering [0, q0+16)
  const int nA  = n >> 1;
  const int t0  = half ? nA : 0;
  const int t1  = half ? n  : nA;

  const ushort* Qb = Q  + (size_t)bh * SEQ * DKH;
  const ushort* Kb = K  + (size_t)bh * SEQ * DKH;
  const ushort* Vb = Vt + (size_t)bh * DKH * SEQ;
  char* Pw = Ps + w * 2048;

  // Q fragments (B-role): lane holds Q[q0+li][d = ks*32 + g*8 .. +8]
  const bf16x8 qf0 = *(const bf16x8*)(Qb + (size_t)(q0 + li) * DKH + g * 8);
  const bf16x8 qf1 = *(const bf16x8*)(Qb + (size_t)(q0 + li) * DKH + 32 + g * 8);

  f32x4 o[4] = {};
  float m_ = -INFINITY, l_ = 0.f;

  bf16x8 kA0[4], kA1[4], vA0[4], vA1[4];   // current tile frags
  bf16x8 kB0[4], kB1[4], vB0[4], vB1[4];   // prefetch tile frags

  auto loadT = [&](int kt, bf16x8 (&k0f)[4], bf16x8 (&k1f)[4],
                   bf16x8 (&v0f)[4], bf16x8 (&v1f)[4]) {
    const int k0 = kt * 64;
    #pragma unroll
    for (int nf = 0; nf < 4; ++nf) {
      const ushort* kr = Kb + (size_t)(k0 + nf * 16 + li) * DKH + g * 8;
      k0f[nf] = *(const bf16x8*)(kr);
      k1f[nf] = *(const bf16x8*)(kr + 32);
      const ushort* vr = Vb + (size_t)(nf * 16 + li) * SEQ + k0 + g * 8;
      v0f[nf] = *(const bf16x8*)(vr);
      v1f[nf] = *(const bf16x8*)(vr + 32);
    }
  };

  auto computeT = [&](int kt, bf16x8 (&k0f)[4], bf16x8 (&k1f)[4],
                      bf16x8 (&v0f)[4], bf16x8 (&v1f)[4]) {
    const int k0 = kt * 64;
    // S^T = K Q^T : st[nf][r] = S[q = q0+li][k = k0 + nf*16 + g*4 + r]
    f32x4 st[4] = {};
    #pragma unroll
    for (int nf = 0; nf < 4; ++nf) {
      st[nf] = __builtin_amdgcn_mfma_f32_16x16x32_bf16(k0f[nf], qf0, st[nf], 0, 0, 0);
      st[nf] = __builtin_amdgcn_mfma_f32_16x16x32_bf16(k1f[nf], qf1, st[nf], 0, 0, 0);
    }
    // causal mask — only ever triggers on the diagonal tile, safe everywhere
    #pragma unroll
    for (int nf = 0; nf < 4; ++nf)
      #pragma unroll
      for (int r = 0; r < 4; ++r)
        if (k0 + nf * 16 + g * 4 + r > q0 + li) st[nf][r] = -1e30f;

    // lane-local online softmax for q = q0 + li
    float mx = fmaxf(fmaxf(fmaxf(st[0][0], st[0][1]), fmaxf(st[0][2], st[0][3])),
                     fmaxf(fmaxf(st[1][0], st[1][1]), fmaxf(st[1][2], st[1][3])));
    mx = fmaxf(mx, fmaxf(fmaxf(fmaxf(st[2][0], st[2][1]), fmaxf(st[2][2], st[2][3])),
                         fmaxf(fmaxf(st[3][0], st[3][1]), fmaxf(st[3][2], st[3][3]))));
    mx = fmaxf(mx, __shfl_xor(mx, 16));
    mx = fmaxf(mx, __shfl_xor(mx, 32));
    const float newm = fmaxf(m_, mx);
    const float al = __expf(m_ - newm);
    m_ = newm;

    float p[4][4];
    float rs = 0.f;
    #pragma unroll
    for (int nf = 0; nf < 4; ++nf)
      #pragma unroll
      for (int r = 0; r < 4; ++r) {
        p[nf][r] = __expf(st[nf][r] - newm);
        rs += p[nf][r];
      }
    rs += __shfl_xor(rs, 16);
    rs += __shfl_xor(rs, 32);
    l_ = l_ * al + rs;

    // rescale O (rows q = g*4 + r need al from lane li = g*4 + r)
    float alr[4];
    #pragma unroll
    for (int r = 0; r < 4; ++r) alr[r] = __shfl(al, g * 4 + r);
    #pragma unroll
    for (int nf = 0; nf < 4; ++nf)
      #pragma unroll
      for (int r = 0; r < 4; ++r) o[nf][r] *= alr[r];

    // P -> wave-private LDS (transpose to A-frag layout), XOR-swizzled
    #pragma unroll
    for (int nf = 0; nf < 4; ++nf) {
      ushort4 pk = { f2b(p[nf][0]), f2b(p[nf][1]), f2b(p[nf][2]), f2b(p[nf][3]) };
      const int cw = nf * 2 + (g >> 1);
      *(ushort4*)(Pw + li * 128 + ((cw ^ (li & 7)) << 4) + ((g & 1) << 3)) = pk;
    }
    bf16x8 pf0 = *(const bf16x8*)(Pw + li * 128 + (((0 * 4 + g) ^ (li & 7)) << 4));
    bf16x8 pf1 = *(const bf16x8*)(Pw + li * 128 + (((1 * 4 + g) ^ (li & 7)) << 4));

    // O += P V
    #pragma unroll
    for (int nf = 0; nf < 4; ++nf) {
      o[nf] = __builtin_amdgcn_mfma_f32_16x16x32_bf16(pf0, v0f[nf], o[nf], 0, 0, 0);
      o[nf] = __builtin_amdgcn_mfma_f32_16x16x32_bf16(pf1, v1f[nf], o[nf], 0, 0, 0);
    }
  };

  // software pipeline: prefetch t+1 while computing t (static reg names)
  int t = t0;
  if (t < t1) loadT(t, kA0, kA1, vA0, vA1);
  for (; t + 2 <= t1; t += 2) {
    loadT(t + 1, kB0, kB1, vB0, vB1);
    computeT(t, kA0, kA1, vA0, vA1);
    if (t + 2 < t1) loadT(t + 2, kA0, kA1, vA0, vA1);
    computeT(t + 1, kB0, kB1, vB0, vB1);
  }
  if (t < t1) computeT(t, kA0, kA1, vA0, vA1);

  // ---- merge the two kv halves of each q-tile ----
  if (half == 1) {
    #pragma unroll
    for (int nf = 0; nf < 4; ++nf)
      *(f32x4*)&OmB[pair][lane][nf * 4] = o[nf];
    mlB[pair][lane][0] = m_;
    mlB[pair][lane][1] = l_;
  }
  __syncthreads();
  if (half == 0) {
    const float mB = mlB[pair][lane][0];
    const float lB = mlB[pair][lane][1];
    const float mN = fmaxf(m_, mB);
    const float a  = __expf(m_ - mN);
    const float bs = __expf(mB - mN);
    const float lN = l_ * a + lB * bs;
    const float inv = 1.0f / lN;

    float ar[4], br[4], ir[4];
    #pragma unroll
    for (int r = 0; r < 4; ++r) {
      ar[r] = __shfl(a,  g * 4 + r);
      br[r] = __shfl(bs, g * 4 + r);
      ir[r] = __shfl(inv, g * 4 + r);
    }

    const int b = bh >> 4, h = bh & 15;
    #pragma unroll
    for (int nf = 0; nf < 4; ++nf) {
      const f32x4 ob = *(const f32x4*)&OmB[pair][lane][nf * 4];
      #pragma unroll
      for (int r = 0; r < 4; ++r) {
        const int q = q0 + g * 4 + r;
        const float v = (o[nf][r] * ar[r] + ob[r] * br[r]) * ir[r];
        AO[((size_t)b * SEQ + q) * DM + h * DKH + nf * 16 + li] = f2b(v);
      }
    }
  }
}

// ---------------------------------------------------------------------------
extern "C" void kernel_launch(void* const* d_in, const int* in_sizes, int n_in,
                              void* d_out, int out_size, void* d_ws, size_t ws_size,
                              hipStream_t stream)
{
  const float* x   = (const float*)d_in[0];
  const int*   pos = (const int*)  d_in[1];
  const float* Wq  = (const float*)d_in[2];
  const float* Wk  = (const float*)d_in[3];
  const float* Wv  = (const float*)d_in[4];
  const float* Wo  = (const float*)d_in[5];
  float* out = (float*)d_out;

  ushort* ws  = (ushort*)d_ws;
  ushort* xb  = ws;                    // 4M
  ushort* wqb = xb  + 4194304;         // 1M each
  ushort* wkb = wqb + 1048576;
  ushort* wvb = wkb + 1048576;
  ushort* wob = wvb + 1048576;
  ushort* Qb  = wob + 1048576;         // 4M each
  ushort* Kb  = Qb  + 4194304;
  ushort* Vtb = Kb  + 4194304;
  ushort* AOb = Vtb + 4194304;

  cvt_all<<<8192, 256, 0, stream>>>(x, Wq, Wk, Wv, Wo, xb, wqb, wkb, wvb, wob);
  gemm_qkv<<<dim3(8, 32, 3), 256, 0, stream>>>(xb, wqb, wkb, wvb, Qb, Kb, Vtb, pos);
  attn<<<2048, 256, 0, stream>>>(Qb, Kb, Vtb, AOb);
  gemm_wo<<<dim3(8, 32), 256, 0, stream>>>(AOb, wob, out);
}

// Round 5
// 132.162 us; speedup vs baseline: 10.8540x; 1.5349x over previous
//
#include <hip/hip_runtime.h>
#include <math.h>

#define SEQ 2048
#define NH  16
#define DKH 64
#define DM  1024
#define MR  4096   // BATCH*SEQ

using bf16x8 = __attribute__((ext_vector_type(8))) short;
using f32x4  = __attribute__((ext_vector_type(4))) float;

__device__ __forceinline__ ushort f2b(float f) {
  unsigned u = __float_as_uint(f);
  return (ushort)((u + 0x7fffu + ((u >> 16) & 1u)) >> 16);
}

__device__ __forceinline__ void gll16(const void* g, void* l) {
  __builtin_amdgcn_global_load_lds(
      (const __attribute__((address_space(1))) void*)g,
      (__attribute__((address_space(3))) void*)l, 16, 0, 0);
}

// ---------------------------------------------------------------------------
// fp32 -> bf16 conversion of x and the 4 weight matrices (one launch)
// ---------------------------------------------------------------------------
__global__ __launch_bounds__(256) void cvt_all(
    const float* __restrict__ x,  const float* __restrict__ wq,
    const float* __restrict__ wk, const float* __restrict__ wv,
    const float* __restrict__ wo,
    ushort* __restrict__ xb,  ushort* __restrict__ wqb, ushort* __restrict__ wkb,
    ushort* __restrict__ wvb, ushort* __restrict__ wob)
{
  size_t e = ((size_t)blockIdx.x * 256 + threadIdx.x) * 4;
  const float* s; ushort* d; size_t off;
  if      (e < 4194304) { s = x;  d = xb;  off = e; }
  else if (e < 5242880) { s = wq; d = wqb; off = e - 4194304; }
  else if (e < 6291456) { s = wk; d = wkb; off = e - 5242880; }
  else if (e < 7340032) { s = wv; d = wvb; off = e - 6291456; }
  else                  { s = wo; d = wob; off = e - 7340032; }
  float4 f = *(const float4*)(s + off);
  ushort4 o4 = { f2b(f.x), f2b(f.y), f2b(f.z), f2b(f.w) };
  *(ushort4*)(d + off) = o4;
}

// ---------------------------------------------------------------------------
// QKV projection: out[m][n] = sum_k X[m][k] * W[n][k], bf16 MFMA 16x16x32.
// 128x128 tile, BK=64, 4 waves. Epilogue: RoPE (z=0,1), Q pre-scaled 0.125,
// V written transposed [b][h][d][s]. Outputs bf16.
// ---------------------------------------------------------------------------
__global__ __launch_bounds__(256) void gemm_qkv(
    const ushort* __restrict__ X,
    const ushort* __restrict__ Wq, const ushort* __restrict__ Wk, const ushort* __restrict__ Wv,
    ushort* __restrict__ Q, ushort* __restrict__ K, ushort* __restrict__ Vt,
    const int* __restrict__ pos)
{
  __shared__ __align__(16) char smem[32768];
  char* As = smem;
  char* Bs = smem + 16384;

  const int z = blockIdx.z;
  const ushort* W = (z == 0) ? Wq : (z == 1) ? Wk : Wv;

  const int n0 = blockIdx.x * 128;
  const int m0 = blockIdx.y * 128;
  const int tid  = threadIdx.x;
  const int lane = tid & 63;
  const int w    = tid >> 6;
  const int wm = (w >> 1) * 64;
  const int wn = (w & 1) * 64;
  const int li = lane & 15;
  const int g  = lane >> 4;

  f32x4 acc[4][4] = {};

  for (int k0 = 0; k0 < DM; k0 += 64) {
    __syncthreads();
    #pragma unroll
    for (int it = 0; it < 4; ++it) {
      const int L  = w * 4096 + it * 1024 + lane * 16;
      const int r  = L >> 7;
      const int sc = ((L >> 4) & 7) ^ (r & 7);
      gll16(X + (size_t)(m0 + r) * DM + k0 + sc * 8, As + w * 4096 + it * 1024);
      gll16(W + (size_t)(n0 + r) * DM + k0 + sc * 8, Bs + w * 4096 + it * 1024);
    }
    __syncthreads();

    #pragma unroll
    for (int ks = 0; ks < 2; ++ks) {
      bf16x8 af[4], bfr[4];
      #pragma unroll
      for (int mf = 0; mf < 4; ++mf) {
        const int row = wm + mf * 16 + li;
        af[mf] = *(const bf16x8*)(As + row * 128 + (((ks * 4 + g) ^ (row & 7)) << 4));
      }
      #pragma unroll
      for (int nf = 0; nf < 4; ++nf) {
        const int row = wn + nf * 16 + li;
        bfr[nf] = *(const bf16x8*)(Bs + row * 128 + (((ks * 4 + g) ^ (row & 7)) << 4));
      }
      #pragma unroll
      for (int mf = 0; mf < 4; ++mf)
        #pragma unroll
        for (int nf = 0; nf < 4; ++nf)
          acc[mf][nf] = __builtin_amdgcn_mfma_f32_16x16x32_bf16(af[mf], bfr[nf], acc[mf][nf], 0, 0, 0);
    }
  }

  #pragma unroll
  for (int nf = 0; nf < 4; ++nf) {
    const int n = n0 + wn + nf * 16 + li;   // output channel
    const int h = n >> 6;
    const int d = n & 63;
    if (z == 2) {
      #pragma unroll
      for (int mf = 0; mf < 4; ++mf) {
        const int m  = m0 + wm + mf * 16 + g * 4;
        const int b  = m >> 11;
        const int s2 = m & (SEQ - 1);
        ushort4 pk = { f2b(acc[mf][nf][0]), f2b(acc[mf][nf][1]),
                       f2b(acc[mf][nf][2]), f2b(acc[mf][nf][3]) };
        *(ushort4*)(Vt + (((size_t)b * NH + h) * DKH + d) * SEQ + s2) = pk;
      }
    } else {
      ushort* DST = (z == 0) ? Q : K;
      const float freq = __expf(-(float)(d >> 1) * 0.2878231366242557f);
      #pragma unroll
      for (int mf = 0; mf < 4; ++mf) {
        #pragma unroll
        for (int r = 0; r < 4; ++r) {
          const int m  = m0 + wm + mf * 16 + g * 4 + r;
          const int b  = m >> 11;
          const int s2 = m & (SEQ - 1);
          const float ang = (float)pos[s2] * freq;
          float sn, cs;
          __sincosf(ang, &sn, &cs);
          const float v1 = acc[mf][nf][r];
          const float v2 = __shfl_xor(v1, 1);
          float ov = (d & 1) ? (v2 * sn + v1 * cs)
                             : (v1 * cs - v2 * sn);
          if (z == 0) ov *= 0.125f;
          DST[(((size_t)b * NH + h) * SEQ + s2) * DKH + d] = f2b(ov);
        }
      }
    }
  }
}

// ---------------------------------------------------------------------------
// Wo projection: fp32 output, same GEMM core.
// ---------------------------------------------------------------------------
__global__ __launch_bounds__(256) void gemm_wo(
    const ushort* __restrict__ A, const ushort* __restrict__ W,
    float* __restrict__ out)
{
  __shared__ __align__(16) char smem[32768];
  char* As = smem;
  char* Bs = smem + 16384;

  const int n0 = blockIdx.x * 128;
  const int m0 = blockIdx.y * 128;
  const int tid  = threadIdx.x;
  const int lane = tid & 63;
  const int w    = tid >> 6;
  const int wm = (w >> 1) * 64;
  const int wn = (w & 1) * 64;
  const int li = lane & 15;
  const int g  = lane >> 4;

  f32x4 acc[4][4] = {};

  for (int k0 = 0; k0 < DM; k0 += 64) {
    __syncthreads();
    #pragma unroll
    for (int it = 0; it < 4; ++it) {
      const int L  = w * 4096 + it * 1024 + lane * 16;
      const int r  = L >> 7;
      const int sc = ((L >> 4) & 7) ^ (r & 7);
      gll16(A + (size_t)(m0 + r) * DM + k0 + sc * 8, As + w * 4096 + it * 1024);
      gll16(W + (size_t)(n0 + r) * DM + k0 + sc * 8, Bs + w * 4096 + it * 1024);
    }
    __syncthreads();

    #pragma unroll
    for (int ks = 0; ks < 2; ++ks) {
      bf16x8 af[4], bfr[4];
      #pragma unroll
      for (int mf = 0; mf < 4; ++mf) {
        const int row = wm + mf * 16 + li;
        af[mf] = *(const bf16x8*)(As + row * 128 + (((ks * 4 + g) ^ (row & 7)) << 4));
      }
      #pragma unroll
      for (int nf = 0; nf < 4; ++nf) {
        const int row = wn + nf * 16 + li;
        bfr[nf] = *(const bf16x8*)(Bs + row * 128 + (((ks * 4 + g) ^ (row & 7)) << 4));
      }
      #pragma unroll
      for (int mf = 0; mf < 4; ++mf)
        #pragma unroll
        for (int nf = 0; nf < 4; ++nf)
          acc[mf][nf] = __builtin_amdgcn_mfma_f32_16x16x32_bf16(af[mf], bfr[nf], acc[mf][nf], 0, 0, 0);
    }
  }

  #pragma unroll
  for (int nf = 0; nf < 4; ++nf)
    #pragma unroll
    for (int mf = 0; mf < 4; ++mf)
      #pragma unroll
      for (int r = 0; r < 4; ++r)
        out[(size_t)(m0 + wm + mf * 16 + g * 4 + r) * DM + n0 + wn + nf * 16 + li] = acc[mf][nf][r];
}

// ---------------------------------------------------------------------------
// Causal flash attention, bf16 MFMA.
// Q,K: [b][h][s][64] bf16 (Q pre-scaled 0.125). Vt: [b][h][64][s] bf16.
// Block = 4 waves, one (b,h), 64 q-rows (wave w owns rows [w*16, w*16+16)).
// K/V staged ONCE PER BLOCK into double-buffered swizzled LDS via contiguous
// global_load_lds (kills the 4x L2 sector amplification of per-lane strided
// fragment gathers). Pipeline: stage(t+1) -> counted vmcnt(4) -> raw barrier
// -> compute(t) -> barrier (prefetch stays in flight across the barrier).
// Swapped QK^T (mfma(K,Q)) -> lane-local softmax; P via wave-private LDS.
// Heavy blocks first (LPT); same-head blocks pinned per XCD.
// ---------------------------------------------------------------------------
__global__ __launch_bounds__(256) void attn(
    const ushort* __restrict__ Q, const ushort* __restrict__ K,
    const ushort* __restrict__ Vt, ushort* __restrict__ AO)
{
  __shared__ __align__(16) char KsB[2][8192];   // 64 rows x 128B, swizzled
  __shared__ __align__(16) char VsB[2][8192];   // 64 d-rows x 128B, swizzled
  __shared__ __align__(16) char Ps[8192];       // 4 waves x 2KB P-transpose

  const int tid  = threadIdx.x;
  const int lane = tid & 63;
  const int w    = tid >> 6;
  const int li   = lane & 15;
  const int g    = lane >> 4;

  const int bx  = blockIdx.x;          // 1024 blocks
  const int xcd = bx & 7;
  const int idx = bx >> 3;             // 0..127
  const int bh  = (idx & 3) * 8 + xcd; // 4 heads per XCD slot
  const int qb  = 31 - (idx >> 2);     // heavy (long) blocks first
  const int q0b = qb * 64;             // block's first q-row
  const int n   = qb + 1;              // number of 64-wide kv tiles
  const int q0w = q0b + w * 16;        // wave's first q-row

  const ushort* Qb = Q  + (size_t)bh * SEQ * DKH;
  const ushort* Kb = K  + (size_t)bh * SEQ * DKH;
  const ushort* Vb = Vt + (size_t)bh * DKH * SEQ;
  char* Pw = Ps + w * 2048;

  // Q fragments (B-role): lane holds Q[q0w+li][d = ks*32 + g*8 .. +8]
  const bf16x8 qf0 = *(const bf16x8*)(Qb + (size_t)(q0w + li) * DKH + g * 8);
  const bf16x8 qf1 = *(const bf16x8*)(Qb + (size_t)(q0w + li) * DKH + 32 + g * 8);

  f32x4 o[4] = {};
  float m_ = -INFINITY, l_ = 0.f;

  // stage kv tile kt into buffer buf: each wave stages its 2KB quarter,
  // contiguous 1KB per gll16 (global src pre-swizzled; LDS dest linear).
  auto stage = [&](int kt, int buf) {
    const int k0 = kt * 64;
    #pragma unroll
    for (int it = 0; it < 2; ++it) {
      const int L  = w * 2048 + it * 1024 + lane * 16;
      const int r  = L >> 7;
      const int sc = ((L >> 4) & 7) ^ (r & 7);
      gll16(Kb + (size_t)(k0 + r) * DKH + sc * 8, &KsB[buf][w * 2048 + it * 1024]);
      gll16(Vb + (size_t)r * SEQ + k0 + sc * 8,   &VsB[buf][w * 2048 + it * 1024]);
    }
  };

  auto computeT = [&](int t) {
    const int k0 = t * 64;
    const char* Kc = KsB[t & 1];
    const char* Vc = VsB[t & 1];

    // S^T = K Q^T : st[nf][r] = S[q = q0w+li][k = k0 + nf*16 + g*4 + r]
    f32x4 st[4] = {};
    #pragma unroll
    for (int nf = 0; nf < 4; ++nf) {
      const int row = nf * 16 + li;
      bf16x8 kfa = *(const bf16x8*)(Kc + row * 128 + (((0 + g) ^ (row & 7)) << 4));
      bf16x8 kfb = *(const bf16x8*)(Kc + row * 128 + (((4 + g) ^ (row & 7)) << 4));
      st[nf] = __builtin_amdgcn_mfma_f32_16x16x32_bf16(kfa, qf0, st[nf], 0, 0, 0);
      st[nf] = __builtin_amdgcn_mfma_f32_16x16x32_bf16(kfb, qf1, st[nf], 0, 0, 0);
    }

    // causal mask (only bites on diagonal tiles; cheap & uniform elsewhere)
    #pragma unroll
    for (int nf = 0; nf < 4; ++nf)
      #pragma unroll
      for (int r = 0; r < 4; ++r)
        if (k0 + nf * 16 + g * 4 + r > q0w + li) st[nf][r] = -1e30f;

    // lane-local online softmax for q = q0w + li
    float mx = fmaxf(fmaxf(fmaxf(st[0][0], st[0][1]), fmaxf(st[0][2], st[0][3])),
                     fmaxf(fmaxf(st[1][0], st[1][1]), fmaxf(st[1][2], st[1][3])));
    mx = fmaxf(mx, fmaxf(fmaxf(fmaxf(st[2][0], st[2][1]), fmaxf(st[2][2], st[2][3])),
                         fmaxf(fmaxf(st[3][0], st[3][1]), fmaxf(st[3][2], st[3][3]))));
    mx = fmaxf(mx, __shfl_xor(mx, 16));
    mx = fmaxf(mx, __shfl_xor(mx, 32));
    const float newm = fmaxf(m_, mx);
    const float al = __expf(m_ - newm);
    m_ = newm;

    float p[4][4];
    float rs = 0.f;
    #pragma unroll
    for (int nf = 0; nf < 4; ++nf)
      #pragma unroll
      for (int r = 0; r < 4; ++r) {
        p[nf][r] = __expf(st[nf][r] - newm);
        rs += p[nf][r];
      }
    rs += __shfl_xor(rs, 16);
    rs += __shfl_xor(rs, 32);
    l_ = l_ * al + rs;

    float alr[4];
    #pragma unroll
    for (int r = 0; r < 4; ++r) alr[r] = __shfl(al, g * 4 + r);
    #pragma unroll
    for (int nf = 0; nf < 4; ++nf)
      #pragma unroll
      for (int r = 0; r < 4; ++r) o[nf][r] *= alr[r];

    // P -> wave-private LDS (transpose to A-frag layout), XOR-swizzled
    #pragma unroll
    for (int nf = 0; nf < 4; ++nf) {
      ushort4 pk = { f2b(p[nf][0]), f2b(p[nf][1]), f2b(p[nf][2]), f2b(p[nf][3]) };
      const int cw = nf * 2 + (g >> 1);
      *(ushort4*)(Pw + li * 128 + ((cw ^ (li & 7)) << 4) + ((g & 1) << 3)) = pk;
    }
    bf16x8 pf0 = *(const bf16x8*)(Pw + li * 128 + (((0 + g) ^ (li & 7)) << 4));
    bf16x8 pf1 = *(const bf16x8*)(Pw + li * 128 + (((4 + g) ^ (li & 7)) << 4));

    // O += P V
    #pragma unroll
    for (int nf = 0; nf < 4; ++nf) {
      const int row = nf * 16 + li;
      bf16x8 vfa = *(const bf16x8*)(Vc + row * 128 + (((0 + g) ^ (row & 7)) << 4));
      bf16x8 vfb = *(const bf16x8*)(Vc + row * 128 + (((4 + g) ^ (row & 7)) << 4));
      o[nf] = __builtin_amdgcn_mfma_f32_16x16x32_bf16(pf0, vfa, o[nf], 0, 0, 0);
      o[nf] = __builtin_amdgcn_mfma_f32_16x16x32_bf16(pf1, vfb, o[nf], 0, 0, 0);
    }
  };

  // ---- pipelined main loop: 2 barriers + 1 counted vmcnt per tile ----
  stage(0, 0);
  for (int t = 0; t < n; ++t) {
    if (t + 1 < n) {
      stage(t + 1, (t + 1) & 1);
      __builtin_amdgcn_sched_barrier(0);
      asm volatile("s_waitcnt vmcnt(4)" ::: "memory");   // stage(t) done; t+1 in flight
    } else {
      asm volatile("s_waitcnt vmcnt(0)" ::: "memory");
    }
    __builtin_amdgcn_s_barrier();                        // all waves' stage(t) done
    __builtin_amdgcn_sched_barrier(0);
    if (t * 64 <= q0w + 15) computeT(t);                 // wave-uniform skip of masked tiles
    __builtin_amdgcn_sched_barrier(0);
    __builtin_amdgcn_s_barrier();                        // all waves done reading buf[t&1]
  }

  // finalize: rows q = g*4+r need 1/l from lane li = g*4+r
  const float inv = 1.0f / l_;
  float ir[4];
  #pragma unroll
  for (int r = 0; r < 4; ++r) ir[r] = __shfl(inv, g * 4 + r);

  const int b = bh >> 4, h = bh & 15;
  #pragma unroll
  for (int nf = 0; nf < 4; ++nf)
    #pragma unroll
    for (int r = 0; r < 4; ++r) {
      const int q = q0w + g * 4 + r;
      AO[((size_t)b * SEQ + q) * DM + h * DKH + nf * 16 + li] = f2b(o[nf][r] * ir[r]);
    }
}

// ---------------------------------------------------------------------------
extern "C" void kernel_launch(void* const* d_in, const int* in_sizes, int n_in,
                              void* d_out, int out_size, void* d_ws, size_t ws_size,
                              hipStream_t stream)
{
  const float* x   = (const float*)d_in[0];
  const int*   pos = (const int*)  d_in[1];
  const float* Wq  = (const float*)d_in[2];
  const float* Wk  = (const float*)d_in[3];
  const float* Wv  = (const float*)d_in[4];
  const float* Wo  = (const float*)d_in[5];
  float* out = (float*)d_out;

  ushort* ws  = (ushort*)d_ws;
  ushort* xb  = ws;                    // 4M
  ushort* wqb = xb  + 4194304;         // 1M each
  ushort* wkb = wqb + 1048576;
  ushort* wvb = wkb + 1048576;
  ushort* wob = wvb + 1048576;
  ushort* Qb  = wob + 1048576;         // 4M each
  ushort* Kb  = Qb  + 4194304;
  ushort* Vtb = Kb  + 4194304;
  ushort* AOb = Vtb + 4194304;

  cvt_all<<<8192, 256, 0, stream>>>(x, Wq, Wk, Wv, Wo, xb, wqb, wkb, wvb, wob);
  gemm_qkv<<<dim3(8, 32, 3), 256, 0, stream>>>(xb, wqb, wkb, wvb, Qb, Kb, Vtb, pos);
  attn<<<1024, 256, 0, stream>>>(Qb, Kb, Vtb, AOb);
  gemm_wo<<<dim3(8, 32), 256, 0, stream>>>(AOb, wob, out);
}

// Round 6
// 128.861 us; speedup vs baseline: 11.1321x; 1.0256x over previous
//
#include <hip/hip_runtime.h>
#include <math.h>

#define SEQ 2048
#define NH  16
#define DKH 64
#define DM  1024
#define MR  4096   // BATCH*SEQ

using bf16x8 = __attribute__((ext_vector_type(8))) short;
using f32x4  = __attribute__((ext_vector_type(4))) float;

__device__ __forceinline__ ushort f2b(float f) {
  unsigned u = __float_as_uint(f);
  return (ushort)((u + 0x7fffu + ((u >> 16) & 1u)) >> 16);
}

__device__ __forceinline__ void gll16(const void* g, void* l) {
  __builtin_amdgcn_global_load_lds(
      (const __attribute__((address_space(1))) void*)g,
      (__attribute__((address_space(3))) void*)l, 16, 0, 0);
}

// ---------------------------------------------------------------------------
// fp32 -> bf16 conversion of x and the 4 weight matrices (one launch)
// ---------------------------------------------------------------------------
__global__ __launch_bounds__(256) void cvt_all(
    const float* __restrict__ x,  const float* __restrict__ wq,
    const float* __restrict__ wk, const float* __restrict__ wv,
    const float* __restrict__ wo,
    ushort* __restrict__ xb,  ushort* __restrict__ wqb, ushort* __restrict__ wkb,
    ushort* __restrict__ wvb, ushort* __restrict__ wob)
{
  size_t e = ((size_t)blockIdx.x * 256 + threadIdx.x) * 4;
  const float* s; ushort* d; size_t off;
  if      (e < 4194304) { s = x;  d = xb;  off = e; }
  else if (e < 5242880) { s = wq; d = wqb; off = e - 4194304; }
  else if (e < 6291456) { s = wk; d = wkb; off = e - 5242880; }
  else if (e < 7340032) { s = wv; d = wvb; off = e - 6291456; }
  else                  { s = wo; d = wob; off = e - 7340032; }
  float4 f = *(const float4*)(s + off);
  ushort4 o4 = { f2b(f.x), f2b(f.y), f2b(f.z), f2b(f.w) };
  *(ushort4*)(d + off) = o4;
}

// ---------------------------------------------------------------------------
// QKV projection: out[m][n] = sum_k X[m][k] * W[n][k], bf16 MFMA 16x16x32.
// 128x128 tile, BK=64, 4 waves. 2-phase pipeline: stage(t+1) into the other
// LDS buffer -> counted vmcnt(8) (t's loads done, t+1's in flight) -> raw
// barrier -> compute(t) -> barrier. Epilogue: RoPE (z=0,1), Q pre-scaled
// 0.125, V written transposed [b][h][d][s]. Outputs bf16.
// ---------------------------------------------------------------------------
__global__ __launch_bounds__(256) void gemm_qkv(
    const ushort* __restrict__ X,
    const ushort* __restrict__ Wq, const ushort* __restrict__ Wk, const ushort* __restrict__ Wv,
    ushort* __restrict__ Q, ushort* __restrict__ K, ushort* __restrict__ Vt,
    const int* __restrict__ pos)
{
  __shared__ __align__(16) char As[2][16384];
  __shared__ __align__(16) char Bs[2][16384];

  const int z = blockIdx.z;
  const ushort* W = (z == 0) ? Wq : (z == 1) ? Wk : Wv;

  const int n0 = blockIdx.x * 128;
  const int m0 = blockIdx.y * 128;
  const int tid  = threadIdx.x;
  const int lane = tid & 63;
  const int w    = tid >> 6;
  const int wm = (w >> 1) * 64;
  const int wn = (w & 1) * 64;
  const int li = lane & 15;
  const int g  = lane >> 4;

  f32x4 acc[4][4] = {};

  auto stage = [&](int t, int buf) {
    const int k0 = t * 64;
    #pragma unroll
    for (int it = 0; it < 4; ++it) {
      const int L  = w * 4096 + it * 1024 + lane * 16;
      const int r  = L >> 7;
      const int sc = ((L >> 4) & 7) ^ (r & 7);
      gll16(X + (size_t)(m0 + r) * DM + k0 + sc * 8, &As[buf][w * 4096 + it * 1024]);
      gll16(W + (size_t)(n0 + r) * DM + k0 + sc * 8, &Bs[buf][w * 4096 + it * 1024]);
    }
  };

  auto compute = [&](int buf) {
    #pragma unroll
    for (int ks = 0; ks < 2; ++ks) {
      bf16x8 af[4], bfr[4];
      #pragma unroll
      for (int mf = 0; mf < 4; ++mf) {
        const int row = wm + mf * 16 + li;
        af[mf] = *(const bf16x8*)(&As[buf][row * 128 + (((ks * 4 + g) ^ (row & 7)) << 4)]);
      }
      #pragma unroll
      for (int nf = 0; nf < 4; ++nf) {
        const int row = wn + nf * 16 + li;
        bfr[nf] = *(const bf16x8*)(&Bs[buf][row * 128 + (((ks * 4 + g) ^ (row & 7)) << 4)]);
      }
      #pragma unroll
      for (int mf = 0; mf < 4; ++mf)
        #pragma unroll
        for (int nf = 0; nf < 4; ++nf)
          acc[mf][nf] = __builtin_amdgcn_mfma_f32_16x16x32_bf16(af[mf], bfr[nf], acc[mf][nf], 0, 0, 0);
    }
  };

  stage(0, 0);
  for (int t = 0; t < 16; ++t) {
    if (t < 15) {
      stage(t + 1, (t + 1) & 1);
      __builtin_amdgcn_sched_barrier(0);
      asm volatile("s_waitcnt vmcnt(8)" ::: "memory");   // stage(t) landed; t+1 in flight
    } else {
      asm volatile("s_waitcnt vmcnt(0)" ::: "memory");
    }
    __builtin_amdgcn_s_barrier();
    __builtin_amdgcn_sched_barrier(0);
    compute(t & 1);
    __builtin_amdgcn_sched_barrier(0);
    __builtin_amdgcn_s_barrier();
  }

  #pragma unroll
  for (int nf = 0; nf < 4; ++nf) {
    const int n = n0 + wn + nf * 16 + li;   // output channel
    const int h = n >> 6;
    const int d = n & 63;
    if (z == 2) {
      #pragma unroll
      for (int mf = 0; mf < 4; ++mf) {
        const int m  = m0 + wm + mf * 16 + g * 4;
        const int b  = m >> 11;
        const int s2 = m & (SEQ - 1);
        ushort4 pk = { f2b(acc[mf][nf][0]), f2b(acc[mf][nf][1]),
                       f2b(acc[mf][nf][2]), f2b(acc[mf][nf][3]) };
        *(ushort4*)(Vt + (((size_t)b * NH + h) * DKH + d) * SEQ + s2) = pk;
      }
    } else {
      ushort* DST = (z == 0) ? Q : K;
      const float freq = __expf(-(float)(d >> 1) * 0.2878231366242557f);
      #pragma unroll
      for (int mf = 0; mf < 4; ++mf) {
        #pragma unroll
        for (int r = 0; r < 4; ++r) {
          const int m  = m0 + wm + mf * 16 + g * 4 + r;
          const int b  = m >> 11;
          const int s2 = m & (SEQ - 1);
          const float ang = (float)pos[s2] * freq;
          float sn, cs;
          __sincosf(ang, &sn, &cs);
          const float v1 = acc[mf][nf][r];
          const float v2 = __shfl_xor(v1, 1);
          float ov = (d & 1) ? (v2 * sn + v1 * cs)
                             : (v1 * cs - v2 * sn);
          if (z == 0) ov *= 0.125f;
          DST[(((size_t)b * NH + h) * SEQ + s2) * DKH + d] = f2b(ov);
        }
      }
    }
  }
}

// ---------------------------------------------------------------------------
// Wo projection: fp32 output, same pipelined GEMM core.
// ---------------------------------------------------------------------------
__global__ __launch_bounds__(256) void gemm_wo(
    const ushort* __restrict__ A, const ushort* __restrict__ W,
    float* __restrict__ out)
{
  __shared__ __align__(16) char As[2][16384];
  __shared__ __align__(16) char Bs[2][16384];

  const int n0 = blockIdx.x * 128;
  const int m0 = blockIdx.y * 128;
  const int tid  = threadIdx.x;
  const int lane = tid & 63;
  const int w    = tid >> 6;
  const int wm = (w >> 1) * 64;
  const int wn = (w & 1) * 64;
  const int li = lane & 15;
  const int g  = lane >> 4;

  f32x4 acc[4][4] = {};

  auto stage = [&](int t, int buf) {
    const int k0 = t * 64;
    #pragma unroll
    for (int it = 0; it < 4; ++it) {
      const int L  = w * 4096 + it * 1024 + lane * 16;
      const int r  = L >> 7;
      const int sc = ((L >> 4) & 7) ^ (r & 7);
      gll16(A + (size_t)(m0 + r) * DM + k0 + sc * 8, &As[buf][w * 4096 + it * 1024]);
      gll16(W + (size_t)(n0 + r) * DM + k0 + sc * 8, &Bs[buf][w * 4096 + it * 1024]);
    }
  };

  auto compute = [&](int buf) {
    #pragma unroll
    for (int ks = 0; ks < 2; ++ks) {
      bf16x8 af[4], bfr[4];
      #pragma unroll
      for (int mf = 0; mf < 4; ++mf) {
        const int row = wm + mf * 16 + li;
        af[mf] = *(const bf16x8*)(&As[buf][row * 128 + (((ks * 4 + g) ^ (row & 7)) << 4)]);
      }
      #pragma unroll
      for (int nf = 0; nf < 4; ++nf) {
        const int row = wn + nf * 16 + li;
        bfr[nf] = *(const bf16x8*)(&Bs[buf][row * 128 + (((ks * 4 + g) ^ (row & 7)) << 4)]);
      }
      #pragma unroll
      for (int mf = 0; mf < 4; ++mf)
        #pragma unroll
        for (int nf = 0; nf < 4; ++nf)
          acc[mf][nf] = __builtin_amdgcn_mfma_f32_16x16x32_bf16(af[mf], bfr[nf], acc[mf][nf], 0, 0, 0);
    }
  };

  stage(0, 0);
  for (int t = 0; t < 16; ++t) {
    if (t < 15) {
      stage(t + 1, (t + 1) & 1);
      __builtin_amdgcn_sched_barrier(0);
      asm volatile("s_waitcnt vmcnt(8)" ::: "memory");
    } else {
      asm volatile("s_waitcnt vmcnt(0)" ::: "memory");
    }
    __builtin_amdgcn_s_barrier();
    __builtin_amdgcn_sched_barrier(0);
    compute(t & 1);
    __builtin_amdgcn_sched_barrier(0);
    __builtin_amdgcn_s_barrier();
  }

  #pragma unroll
  for (int nf = 0; nf < 4; ++nf)
    #pragma unroll
    for (int mf = 0; mf < 4; ++mf)
      #pragma unroll
      for (int r = 0; r < 4; ++r)
        out[(size_t)(m0 + wm + mf * 16 + g * 4 + r) * DM + n0 + wn + nf * 16 + li] = acc[mf][nf][r];
}

// ---------------------------------------------------------------------------
// Causal flash attention, bf16 MFMA (unchanged from round 5).
// ---------------------------------------------------------------------------
__global__ __launch_bounds__(256) void attn(
    const ushort* __restrict__ Q, const ushort* __restrict__ K,
    const ushort* __restrict__ Vt, ushort* __restrict__ AO)
{
  __shared__ __align__(16) char KsB[2][8192];   // 64 rows x 128B, swizzled
  __shared__ __align__(16) char VsB[2][8192];   // 64 d-rows x 128B, swizzled
  __shared__ __align__(16) char Ps[8192];       // 4 waves x 2KB P-transpose

  const int tid  = threadIdx.x;
  const int lane = tid & 63;
  const int w    = tid >> 6;
  const int li   = lane & 15;
  const int g    = lane >> 4;

  const int bx  = blockIdx.x;          // 1024 blocks
  const int xcd = bx & 7;
  const int idx = bx >> 3;             // 0..127
  const int bh  = (idx & 3) * 8 + xcd; // 4 heads per XCD slot
  const int qb  = 31 - (idx >> 2);     // heavy (long) blocks first
  const int q0b = qb * 64;             // block's first q-row
  const int n   = qb + 1;              // number of 64-wide kv tiles
  const int q0w = q0b + w * 16;        // wave's first q-row

  const ushort* Qb = Q  + (size_t)bh * SEQ * DKH;
  const ushort* Kb = K  + (size_t)bh * SEQ * DKH;
  const ushort* Vb = Vt + (size_t)bh * DKH * SEQ;
  char* Pw = Ps + w * 2048;

  const bf16x8 qf0 = *(const bf16x8*)(Qb + (size_t)(q0w + li) * DKH + g * 8);
  const bf16x8 qf1 = *(const bf16x8*)(Qb + (size_t)(q0w + li) * DKH + 32 + g * 8);

  f32x4 o[4] = {};
  float m_ = -INFINITY, l_ = 0.f;

  auto stage = [&](int kt, int buf) {
    const int k0 = kt * 64;
    #pragma unroll
    for (int it = 0; it < 2; ++it) {
      const int L  = w * 2048 + it * 1024 + lane * 16;
      const int r  = L >> 7;
      const int sc = ((L >> 4) & 7) ^ (r & 7);
      gll16(Kb + (size_t)(k0 + r) * DKH + sc * 8, &KsB[buf][w * 2048 + it * 1024]);
      gll16(Vb + (size_t)r * SEQ + k0 + sc * 8,   &VsB[buf][w * 2048 + it * 1024]);
    }
  };

  auto computeT = [&](int t) {
    const int k0 = t * 64;
    const char* Kc = KsB[t & 1];
    const char* Vc = VsB[t & 1];

    f32x4 st[4] = {};
    #pragma unroll
    for (int nf = 0; nf < 4; ++nf) {
      const int row = nf * 16 + li;
      bf16x8 kfa = *(const bf16x8*)(Kc + row * 128 + (((0 + g) ^ (row & 7)) << 4));
      bf16x8 kfb = *(const bf16x8*)(Kc + row * 128 + (((4 + g) ^ (row & 7)) << 4));
      st[nf] = __builtin_amdgcn_mfma_f32_16x16x32_bf16(kfa, qf0, st[nf], 0, 0, 0);
      st[nf] = __builtin_amdgcn_mfma_f32_16x16x32_bf16(kfb, qf1, st[nf], 0, 0, 0);
    }

    #pragma unroll
    for (int nf = 0; nf < 4; ++nf)
      #pragma unroll
      for (int r = 0; r < 4; ++r)
        if (k0 + nf * 16 + g * 4 + r > q0w + li) st[nf][r] = -1e30f;

    float mx = fmaxf(fmaxf(fmaxf(st[0][0], st[0][1]), fmaxf(st[0][2], st[0][3])),
                     fmaxf(fmaxf(st[1][0], st[1][1]), fmaxf(st[1][2], st[1][3])));
    mx = fmaxf(mx, fmaxf(fmaxf(fmaxf(st[2][0], st[2][1]), fmaxf(st[2][2], st[2][3])),
                         fmaxf(fmaxf(st[3][0], st[3][1]), fmaxf(st[3][2], st[3][3]))));
    mx = fmaxf(mx, __shfl_xor(mx, 16));
    mx = fmaxf(mx, __shfl_xor(mx, 32));
    const float newm = fmaxf(m_, mx);
    const float al = __expf(m_ - newm);
    m_ = newm;

    float p[4][4];
    float rs = 0.f;
    #pragma unroll
    for (int nf = 0; nf < 4; ++nf)
      #pragma unroll
      for (int r = 0; r < 4; ++r) {
        p[nf][r] = __expf(st[nf][r] - newm);
        rs += p[nf][r];
      }
    rs += __shfl_xor(rs, 16);
    rs += __shfl_xor(rs, 32);
    l_ = l_ * al + rs;

    float alr[4];
    #pragma unroll
    for (int r = 0; r < 4; ++r) alr[r] = __shfl(al, g * 4 + r);
    #pragma unroll
    for (int nf = 0; nf < 4; ++nf)
      #pragma unroll
      for (int r = 0; r < 4; ++r) o[nf][r] *= alr[r];

    #pragma unroll
    for (int nf = 0; nf < 4; ++nf) {
      ushort4 pk = { f2b(p[nf][0]), f2b(p[nf][1]), f2b(p[nf][2]), f2b(p[nf][3]) };
      const int cw = nf * 2 + (g >> 1);
      *(ushort4*)(Pw + li * 128 + ((cw ^ (li & 7)) << 4) + ((g & 1) << 3)) = pk;
    }
    bf16x8 pf0 = *(const bf16x8*)(Pw + li * 128 + (((0 + g) ^ (li & 7)) << 4));
    bf16x8 pf1 = *(const bf16x8*)(Pw + li * 128 + (((4 + g) ^ (li & 7)) << 4));

    #pragma unroll
    for (int nf = 0; nf < 4; ++nf) {
      const int row = nf * 16 + li;
      bf16x8 vfa = *(const bf16x8*)(Vc + row * 128 + (((0 + g) ^ (row & 7)) << 4));
      bf16x8 vfb = *(const bf16x8*)(Vc + row * 128 + (((4 + g) ^ (row & 7)) << 4));
      o[nf] = __builtin_amdgcn_mfma_f32_16x16x32_bf16(pf0, vfa, o[nf], 0, 0, 0);
      o[nf] = __builtin_amdgcn_mfma_f32_16x16x32_bf16(pf1, vfb, o[nf], 0, 0, 0);
    }
  };

  stage(0, 0);
  for (int t = 0; t < n; ++t) {
    if (t + 1 < n) {
      stage(t + 1, (t + 1) & 1);
      __builtin_amdgcn_sched_barrier(0);
      asm volatile("s_waitcnt vmcnt(4)" ::: "memory");
    } else {
      asm volatile("s_waitcnt vmcnt(0)" ::: "memory");
    }
    __builtin_amdgcn_s_barrier();
    __builtin_amdgcn_sched_barrier(0);
    if (t * 64 <= q0w + 15) computeT(t);
    __builtin_amdgcn_sched_barrier(0);
    __builtin_amdgcn_s_barrier();
  }

  const float inv = 1.0f / l_;
  float ir[4];
  #pragma unroll
  for (int r = 0; r < 4; ++r) ir[r] = __shfl(inv, g * 4 + r);

  const int b = bh >> 4, h = bh & 15;
  #pragma unroll
  for (int nf = 0; nf < 4; ++nf)
    #pragma unroll
    for (int r = 0; r < 4; ++r) {
      const int q = q0w + g * 4 + r;
      AO[((size_t)b * SEQ + q) * DM + h * DKH + nf * 16 + li] = f2b(o[nf][r] * ir[r]);
    }
}

// ---------------------------------------------------------------------------
extern "C" void kernel_launch(void* const* d_in, const int* in_sizes, int n_in,
                              void* d_out, int out_size, void* d_ws, size_t ws_size,
                              hipStream_t stream)
{
  const float* x   = (const float*)d_in[0];
  const int*   pos = (const int*)  d_in[1];
  const float* Wq  = (const float*)d_in[2];
  const float* Wk  = (const float*)d_in[3];
  const float* Wv  = (const float*)d_in[4];
  const float* Wo  = (const float*)d_in[5];
  float* out = (float*)d_out;

  ushort* ws  = (ushort*)d_ws;
  ushort* xb  = ws;                    // 4M
  ushort* wqb = xb  + 4194304;         // 1M each
  ushort* wkb = wqb + 1048576;
  ushort* wvb = wkb + 1048576;
  ushort* wob = wvb + 1048576;
  ushort* Qb  = wob + 1048576;         // 4M each
  ushort* Kb  = Qb  + 4194304;
  ushort* Vtb = Kb  + 4194304;
  ushort* AOb = Vtb + 4194304;

  cvt_all<<<8192, 256, 0, stream>>>(x, Wq, Wk, Wv, Wo, xb, wqb, wkb, wvb, wob);
  gemm_qkv<<<dim3(8, 32, 3), 256, 0, stream>>>(xb, wqb, wkb, wvb, Qb, Kb, Vtb, pos);
  attn<<<1024, 256, 0, stream>>>(Qb, Kb, Vtb, AOb);
  gemm_wo<<<dim3(8, 32), 256, 0, stream>>>(AOb, wob, out);
}

// Round 7
// 115.997 us; speedup vs baseline: 12.3666x; 1.1109x over previous
//
#include <hip/hip_runtime.h>
#include <math.h>

#define SEQ 2048
#define NH  16
#define DKH 64
#define DM  1024
#define MR  4096   // BATCH*SEQ

using bf16x8 = __attribute__((ext_vector_type(8))) short;
using f32x4  = __attribute__((ext_vector_type(4))) float;

__device__ __forceinline__ ushort f2b(float f) {
  unsigned u = __float_as_uint(f);
  return (ushort)((u + 0x7fffu + ((u >> 16) & 1u)) >> 16);
}

__device__ __forceinline__ void gll16(const void* g, void* l) {
  __builtin_amdgcn_global_load_lds(
      (const __attribute__((address_space(1))) void*)g,
      (__attribute__((address_space(3))) void*)l, 16, 0, 0);
}

// ---------------------------------------------------------------------------
// fp32 -> bf16 conversion of x and the 4 weight matrices (one launch)
// ---------------------------------------------------------------------------
__global__ __launch_bounds__(256) void cvt_all(
    const float* __restrict__ x,  const float* __restrict__ wq,
    const float* __restrict__ wk, const float* __restrict__ wv,
    const float* __restrict__ wo,
    ushort* __restrict__ xb,  ushort* __restrict__ wqb, ushort* __restrict__ wkb,
    ushort* __restrict__ wvb, ushort* __restrict__ wob)
{
  size_t e = ((size_t)blockIdx.x * 256 + threadIdx.x) * 4;
  const float* s; ushort* d; size_t off;
  if      (e < 4194304) { s = x;  d = xb;  off = e; }
  else if (e < 5242880) { s = wq; d = wqb; off = e - 4194304; }
  else if (e < 6291456) { s = wk; d = wkb; off = e - 5242880; }
  else if (e < 7340032) { s = wv; d = wvb; off = e - 6291456; }
  else                  { s = wo; d = wob; off = e - 7340032; }
  float4 f = *(const float4*)(s + off);
  ushort4 o4 = { f2b(f.x), f2b(f.y), f2b(f.z), f2b(f.w) };
  *(ushort4*)(d + off) = o4;
}

// ---------------------------------------------------------------------------
// Fused QKV projection: out[m][n] = sum_k X[m][k] * W[n][k], bf16 MFMA.
// N = 3072 fused (z = n-tile / 8). 128x128 tile, BK=64, 8 waves (64x32 each)
// -> 512 threads, 2 blocks/CU, 4 waves/SIMD. 2-phase pipeline with counted
// vmcnt(4). Bijective XCD swizzle: XCD k owns m-tiles [4k,4k+4) x all n
// (X slice L2-resident). Epilogue: RoPE (z<2), Q pre-scaled 0.125, V
// transposed [b][h][d][s]. Outputs bf16.
// ---------------------------------------------------------------------------
__global__ __launch_bounds__(512) void gemm_qkv(
    const ushort* __restrict__ X,
    const ushort* __restrict__ Wq, const ushort* __restrict__ Wk, const ushort* __restrict__ Wv,
    ushort* __restrict__ Q, ushort* __restrict__ K, ushort* __restrict__ Vt,
    const int* __restrict__ pos)
{
  __shared__ __align__(16) char As[2][16384];
  __shared__ __align__(16) char Bs[2][16384];

  const int id  = blockIdx.x;          // 768 blocks
  const int xcd = id & 7;
  const int i   = id >> 3;             // 0..95
  const int mt  = xcd * 4 + (i & 3);   // 0..31  (4 m-tiles per XCD)
  const int nt  = i >> 2;              // 0..23
  const int m0  = mt * 128;
  const int nG  = nt * 128;
  const int z   = nG >> 10;            // 0:Q 1:K 2:V
  const int n0  = nG & 1023;
  const ushort* W = (z == 0) ? Wq : (z == 1) ? Wk : Wv;

  const int tid  = threadIdx.x;
  const int lane = tid & 63;
  const int w    = tid >> 6;           // 0..7
  const int wm   = (w >> 2) * 64;      // 2 m-groups
  const int wn   = (w & 3) * 32;       // 4 n-groups
  const int li   = lane & 15;
  const int g    = lane >> 4;

  f32x4 acc[4][2] = {};

  auto stage = [&](int t, int buf) {
    const int k0 = t * 64;
    #pragma unroll
    for (int it = 0; it < 2; ++it) {
      const int L  = w * 2048 + it * 1024 + lane * 16;
      const int r  = L >> 7;
      const int sc = ((L >> 4) & 7) ^ (r & 7);
      gll16(X + (size_t)(m0 + r) * DM + k0 + sc * 8, &As[buf][w * 2048 + it * 1024]);
      gll16(W + (size_t)(n0 + r) * DM + k0 + sc * 8, &Bs[buf][w * 2048 + it * 1024]);
    }
  };

  auto compute = [&](int buf) {
    #pragma unroll
    for (int ks = 0; ks < 2; ++ks) {
      bf16x8 af[4], bfr[2];
      #pragma unroll
      for (int mf = 0; mf < 4; ++mf) {
        const int row = wm + mf * 16 + li;
        af[mf] = *(const bf16x8*)(&As[buf][row * 128 + (((ks * 4 + g) ^ (row & 7)) << 4)]);
      }
      #pragma unroll
      for (int nf = 0; nf < 2; ++nf) {
        const int row = wn + nf * 16 + li;
        bfr[nf] = *(const bf16x8*)(&Bs[buf][row * 128 + (((ks * 4 + g) ^ (row & 7)) << 4)]);
      }
      #pragma unroll
      for (int mf = 0; mf < 4; ++mf)
        #pragma unroll
        for (int nf = 0; nf < 2; ++nf)
          acc[mf][nf] = __builtin_amdgcn_mfma_f32_16x16x32_bf16(af[mf], bfr[nf], acc[mf][nf], 0, 0, 0);
    }
  };

  stage(0, 0);
  for (int t = 0; t < 16; ++t) {
    if (t < 15) {
      stage(t + 1, (t + 1) & 1);
      __builtin_amdgcn_sched_barrier(0);
      asm volatile("s_waitcnt vmcnt(4)" ::: "memory");   // stage(t) landed; t+1 in flight
    } else {
      asm volatile("s_waitcnt vmcnt(0)" ::: "memory");
    }
    __builtin_amdgcn_s_barrier();
    __builtin_amdgcn_sched_barrier(0);
    compute(t & 1);
    __builtin_amdgcn_sched_barrier(0);
    __builtin_amdgcn_s_barrier();
  }

  #pragma unroll
  for (int nf = 0; nf < 2; ++nf) {
    const int n = n0 + wn + nf * 16 + li;   // channel within this z-matrix
    const int h = n >> 6;
    const int d = n & 63;
    if (z == 2) {
      #pragma unroll
      for (int mf = 0; mf < 4; ++mf) {
        const int m  = m0 + wm + mf * 16 + g * 4;
        const int b  = m >> 11;
        const int s2 = m & (SEQ - 1);
        ushort4 pk = { f2b(acc[mf][nf][0]), f2b(acc[mf][nf][1]),
                       f2b(acc[mf][nf][2]), f2b(acc[mf][nf][3]) };
        *(ushort4*)(Vt + (((size_t)b * NH + h) * DKH + d) * SEQ + s2) = pk;
      }
    } else {
      ushort* DST = (z == 0) ? Q : K;
      const float freq = __expf(-(float)(d >> 1) * 0.2878231366242557f);
      #pragma unroll
      for (int mf = 0; mf < 4; ++mf) {
        #pragma unroll
        for (int r = 0; r < 4; ++r) {
          const int m  = m0 + wm + mf * 16 + g * 4 + r;
          const int b  = m >> 11;
          const int s2 = m & (SEQ - 1);
          const float ang = (float)pos[s2] * freq;
          float sn, cs;
          __sincosf(ang, &sn, &cs);
          const float v1 = acc[mf][nf][r];
          const float v2 = __shfl_xor(v1, 1);
          float ov = (d & 1) ? (v2 * sn + v1 * cs)
                             : (v1 * cs - v2 * sn);
          if (z == 0) ov *= 0.125f;
          DST[(((size_t)b * NH + h) * SEQ + s2) * DKH + d] = f2b(ov);
        }
      }
    }
  }
}

// ---------------------------------------------------------------------------
// Wo projection: fp32 output, same 8-wave pipelined GEMM core + XCD swizzle.
// ---------------------------------------------------------------------------
__global__ __launch_bounds__(512) void gemm_wo(
    const ushort* __restrict__ A, const ushort* __restrict__ W,
    float* __restrict__ out)
{
  __shared__ __align__(16) char As[2][16384];
  __shared__ __align__(16) char Bs[2][16384];

  const int id  = blockIdx.x;          // 256 blocks
  const int xcd = id & 7;
  const int i   = id >> 3;             // 0..31
  const int mt  = xcd * 4 + (i & 3);   // 0..31
  const int nt  = i >> 2;              // 0..7
  const int m0  = mt * 128;
  const int n0  = nt * 128;

  const int tid  = threadIdx.x;
  const int lane = tid & 63;
  const int w    = tid >> 6;
  const int wm   = (w >> 2) * 64;
  const int wn   = (w & 3) * 32;
  const int li   = lane & 15;
  const int g    = lane >> 4;

  f32x4 acc[4][2] = {};

  auto stage = [&](int t, int buf) {
    const int k0 = t * 64;
    #pragma unroll
    for (int it = 0; it < 2; ++it) {
      const int L  = w * 2048 + it * 1024 + lane * 16;
      const int r  = L >> 7;
      const int sc = ((L >> 4) & 7) ^ (r & 7);
      gll16(A + (size_t)(m0 + r) * DM + k0 + sc * 8, &As[buf][w * 2048 + it * 1024]);
      gll16(W + (size_t)(n0 + r) * DM + k0 + sc * 8, &Bs[buf][w * 2048 + it * 1024]);
    }
  };

  auto compute = [&](int buf) {
    #pragma unroll
    for (int ks = 0; ks < 2; ++ks) {
      bf16x8 af[4], bfr[2];
      #pragma unroll
      for (int mf = 0; mf < 4; ++mf) {
        const int row = wm + mf * 16 + li;
        af[mf] = *(const bf16x8*)(&As[buf][row * 128 + (((ks * 4 + g) ^ (row & 7)) << 4)]);
      }
      #pragma unroll
      for (int nf = 0; nf < 2; ++nf) {
        const int row = wn + nf * 16 + li;
        bfr[nf] = *(const bf16x8*)(&Bs[buf][row * 128 + (((ks * 4 + g) ^ (row & 7)) << 4)]);
      }
      #pragma unroll
      for (int mf = 0; mf < 4; ++mf)
        #pragma unroll
        for (int nf = 0; nf < 2; ++nf)
          acc[mf][nf] = __builtin_amdgcn_mfma_f32_16x16x32_bf16(af[mf], bfr[nf], acc[mf][nf], 0, 0, 0);
    }
  };

  stage(0, 0);
  for (int t = 0; t < 16; ++t) {
    if (t < 15) {
      stage(t + 1, (t + 1) & 1);
      __builtin_amdgcn_sched_barrier(0);
      asm volatile("s_waitcnt vmcnt(4)" ::: "memory");
    } else {
      asm volatile("s_waitcnt vmcnt(0)" ::: "memory");
    }
    __builtin_amdgcn_s_barrier();
    __builtin_amdgcn_sched_barrier(0);
    compute(t & 1);
    __builtin_amdgcn_sched_barrier(0);
    __builtin_amdgcn_s_barrier();
  }

  #pragma unroll
  for (int nf = 0; nf < 2; ++nf)
    #pragma unroll
    for (int mf = 0; mf < 4; ++mf)
      #pragma unroll
      for (int r = 0; r < 4; ++r)
        out[(size_t)(m0 + wm + mf * 16 + g * 4 + r) * DM + n0 + wn + nf * 16 + li] = acc[mf][nf][r];
}

// ---------------------------------------------------------------------------
// Causal flash attention, bf16 MFMA (unchanged from round 5/6).
// ---------------------------------------------------------------------------
__global__ __launch_bounds__(256) void attn(
    const ushort* __restrict__ Q, const ushort* __restrict__ K,
    const ushort* __restrict__ Vt, ushort* __restrict__ AO)
{
  __shared__ __align__(16) char KsB[2][8192];   // 64 rows x 128B, swizzled
  __shared__ __align__(16) char VsB[2][8192];   // 64 d-rows x 128B, swizzled
  __shared__ __align__(16) char Ps[8192];       // 4 waves x 2KB P-transpose

  const int tid  = threadIdx.x;
  const int lane = tid & 63;
  const int w    = tid >> 6;
  const int li   = lane & 15;
  const int g    = lane >> 4;

  const int bx  = blockIdx.x;          // 1024 blocks
  const int xcd = bx & 7;
  const int idx = bx >> 3;             // 0..127
  const int bh  = (idx & 3) * 8 + xcd; // 4 heads per XCD slot
  const int qb  = 31 - (idx >> 2);     // heavy (long) blocks first
  const int q0b = qb * 64;             // block's first q-row
  const int n   = qb + 1;              // number of 64-wide kv tiles
  const int q0w = q0b + w * 16;        // wave's first q-row

  const ushort* Qb = Q  + (size_t)bh * SEQ * DKH;
  const ushort* Kb = K  + (size_t)bh * SEQ * DKH;
  const ushort* Vb = Vt + (size_t)bh * DKH * SEQ;
  char* Pw = Ps + w * 2048;

  const bf16x8 qf0 = *(const bf16x8*)(Qb + (size_t)(q0w + li) * DKH + g * 8);
  const bf16x8 qf1 = *(const bf16x8*)(Qb + (size_t)(q0w + li) * DKH + 32 + g * 8);

  f32x4 o[4] = {};
  float m_ = -INFINITY, l_ = 0.f;

  auto stage = [&](int kt, int buf) {
    const int k0 = kt * 64;
    #pragma unroll
    for (int it = 0; it < 2; ++it) {
      const int L  = w * 2048 + it * 1024 + lane * 16;
      const int r  = L >> 7;
      const int sc = ((L >> 4) & 7) ^ (r & 7);
      gll16(Kb + (size_t)(k0 + r) * DKH + sc * 8, &KsB[buf][w * 2048 + it * 1024]);
      gll16(Vb + (size_t)r * SEQ + k0 + sc * 8,   &VsB[buf][w * 2048 + it * 1024]);
    }
  };

  auto computeT = [&](int t) {
    const int k0 = t * 64;
    const char* Kc = KsB[t & 1];
    const char* Vc = VsB[t & 1];

    f32x4 st[4] = {};
    #pragma unroll
    for (int nf = 0; nf < 4; ++nf) {
      const int row = nf * 16 + li;
      bf16x8 kfa = *(const bf16x8*)(Kc + row * 128 + (((0 + g) ^ (row & 7)) << 4));
      bf16x8 kfb = *(const bf16x8*)(Kc + row * 128 + (((4 + g) ^ (row & 7)) << 4));
      st[nf] = __builtin_amdgcn_mfma_f32_16x16x32_bf16(kfa, qf0, st[nf], 0, 0, 0);
      st[nf] = __builtin_amdgcn_mfma_f32_16x16x32_bf16(kfb, qf1, st[nf], 0, 0, 0);
    }

    #pragma unroll
    for (int nf = 0; nf < 4; ++nf)
      #pragma unroll
      for (int r = 0; r < 4; ++r)
        if (k0 + nf * 16 + g * 4 + r > q0w + li) st[nf][r] = -1e30f;

    float mx = fmaxf(fmaxf(fmaxf(st[0][0], st[0][1]), fmaxf(st[0][2], st[0][3])),
                     fmaxf(fmaxf(st[1][0], st[1][1]), fmaxf(st[1][2], st[1][3])));
    mx = fmaxf(mx, fmaxf(fmaxf(fmaxf(st[2][0], st[2][1]), fmaxf(st[2][2], st[2][3])),
                         fmaxf(fmaxf(st[3][0], st[3][1]), fmaxf(st[3][2], st[3][3]))));
    mx = fmaxf(mx, __shfl_xor(mx, 16));
    mx = fmaxf(mx, __shfl_xor(mx, 32));
    const float newm = fmaxf(m_, mx);
    const float al = __expf(m_ - newm);
    m_ = newm;

    float p[4][4];
    float rs = 0.f;
    #pragma unroll
    for (int nf = 0; nf < 4; ++nf)
      #pragma unroll
      for (int r = 0; r < 4; ++r) {
        p[nf][r] = __expf(st[nf][r] - newm);
        rs += p[nf][r];
      }
    rs += __shfl_xor(rs, 16);
    rs += __shfl_xor(rs, 32);
    l_ = l_ * al + rs;

    float alr[4];
    #pragma unroll
    for (int r = 0; r < 4; ++r) alr[r] = __shfl(al, g * 4 + r);
    #pragma unroll
    for (int nf = 0; nf < 4; ++nf)
      #pragma unroll
      for (int r = 0; r < 4; ++r) o[nf][r] *= alr[r];

    #pragma unroll
    for (int nf = 0; nf < 4; ++nf) {
      ushort4 pk = { f2b(p[nf][0]), f2b(p[nf][1]), f2b(p[nf][2]), f2b(p[nf][3]) };
      const int cw = nf * 2 + (g >> 1);
      *(ushort4*)(Pw + li * 128 + ((cw ^ (li & 7)) << 4) + ((g & 1) << 3)) = pk;
    }
    bf16x8 pf0 = *(const bf16x8*)(Pw + li * 128 + (((0 + g) ^ (li & 7)) << 4));
    bf16x8 pf1 = *(const bf16x8*)(Pw + li * 128 + (((4 + g) ^ (li & 7)) << 4));

    #pragma unroll
    for (int nf = 0; nf < 4; ++nf) {
      const int row = nf * 16 + li;
      bf16x8 vfa = *(const bf16x8*)(Vc + row * 128 + (((0 + g) ^ (row & 7)) << 4));
      bf16x8 vfb = *(const bf16x8*)(Vc + row * 128 + (((4 + g) ^ (row & 7)) << 4));
      o[nf] = __builtin_amdgcn_mfma_f32_16x16x32_bf16(pf0, vfa, o[nf], 0, 0, 0);
      o[nf] = __builtin_amdgcn_mfma_f32_16x16x32_bf16(pf1, vfb, o[nf], 0, 0, 0);
    }
  };

  stage(0, 0);
  for (int t = 0; t < n; ++t) {
    if (t + 1 < n) {
      stage(t + 1, (t + 1) & 1);
      __builtin_amdgcn_sched_barrier(0);
      asm volatile("s_waitcnt vmcnt(4)" ::: "memory");
    } else {
      asm volatile("s_waitcnt vmcnt(0)" ::: "memory");
    }
    __builtin_amdgcn_s_barrier();
    __builtin_amdgcn_sched_barrier(0);
    if (t * 64 <= q0w + 15) computeT(t);
    __builtin_amdgcn_sched_barrier(0);
    __builtin_amdgcn_s_barrier();
  }

  const float inv = 1.0f / l_;
  float ir[4];
  #pragma unroll
  for (int r = 0; r < 4; ++r) ir[r] = __shfl(inv, g * 4 + r);

  const int b = bh >> 4, h = bh & 15;
  #pragma unroll
  for (int nf = 0; nf < 4; ++nf)
    #pragma unroll
    for (int r = 0; r < 4; ++r) {
      const int q = q0w + g * 4 + r;
      AO[((size_t)b * SEQ + q) * DM + h * DKH + nf * 16 + li] = f2b(o[nf][r] * ir[r]);
    }
}

// ---------------------------------------------------------------------------
extern "C" void kernel_launch(void* const* d_in, const int* in_sizes, int n_in,
                              void* d_out, int out_size, void* d_ws, size_t ws_size,
                              hipStream_t stream)
{
  const float* x   = (const float*)d_in[0];
  const int*   pos = (const int*)  d_in[1];
  const float* Wq  = (const float*)d_in[2];
  const float* Wk  = (const float*)d_in[3];
  const float* Wv  = (const float*)d_in[4];
  const float* Wo  = (const float*)d_in[5];
  float* out = (float*)d_out;

  ushort* ws  = (ushort*)d_ws;
  ushort* xb  = ws;                    // 4M
  ushort* wqb = xb  + 4194304;         // 1M each
  ushort* wkb = wqb + 1048576;
  ushort* wvb = wkb + 1048576;
  ushort* wob = wvb + 1048576;
  ushort* Qb  = wob + 1048576;         // 4M each
  ushort* Kb  = Qb  + 4194304;
  ushort* Vtb = Kb  + 4194304;
  ushort* AOb = Vtb + 4194304;

  cvt_all<<<8192, 256, 0, stream>>>(x, Wq, Wk, Wv, Wo, xb, wqb, wkb, wvb, wob);
  gemm_qkv<<<768, 512, 0, stream>>>(xb, wqb, wkb, wvb, Qb, Kb, Vtb, pos);
  attn<<<1024, 256, 0, stream>>>(Qb, Kb, Vtb, AOb);
  gemm_wo<<<256, 512, 0, stream>>>(AOb, wob, out);
}

// Round 8
// 113.591 us; speedup vs baseline: 12.6286x; 1.0212x over previous
//
#include <hip/hip_runtime.h>
#include <math.h>

#define SEQ 2048
#define NH  16
#define DKH 64
#define DM  1024
#define MR  4096   // BATCH*SEQ

using bf16x8 = __attribute__((ext_vector_type(8))) short;
using f32x4  = __attribute__((ext_vector_type(4))) float;

__device__ __forceinline__ ushort f2b(float f) {
  unsigned u = __float_as_uint(f);
  return (ushort)((u + 0x7fffu + ((u >> 16) & 1u)) >> 16);
}

__device__ __forceinline__ float exp2_fast(float x) {
  float r; asm("v_exp_f32 %0, %1" : "=v"(r) : "v"(x)); return r;
}

__device__ __forceinline__ unsigned cvt_pk(float lo, float hi) {
  unsigned r; asm("v_cvt_pk_bf16_f32 %0, %1, %2" : "=v"(r) : "v"(lo), "v"(hi));
  return r;
}

__device__ __forceinline__ void gll16(const void* g, void* l) {
  __builtin_amdgcn_global_load_lds(
      (const __attribute__((address_space(1))) void*)g,
      (__attribute__((address_space(3))) void*)l, 16, 0, 0);
}

// ---------------------------------------------------------------------------
// fp32 -> bf16 conversion of x and the 4 weight matrices (one launch)
// ---------------------------------------------------------------------------
__global__ __launch_bounds__(256) void cvt_all(
    const float* __restrict__ x,  const float* __restrict__ wq,
    const float* __restrict__ wk, const float* __restrict__ wv,
    const float* __restrict__ wo,
    ushort* __restrict__ xb,  ushort* __restrict__ wqb, ushort* __restrict__ wkb,
    ushort* __restrict__ wvb, ushort* __restrict__ wob)
{
  size_t e = ((size_t)blockIdx.x * 256 + threadIdx.x) * 4;
  const float* s; ushort* d; size_t off;
  if      (e < 4194304) { s = x;  d = xb;  off = e; }
  else if (e < 5242880) { s = wq; d = wqb; off = e - 4194304; }
  else if (e < 6291456) { s = wk; d = wkb; off = e - 5242880; }
  else if (e < 7340032) { s = wv; d = wvb; off = e - 6291456; }
  else                  { s = wo; d = wob; off = e - 7340032; }
  float4 f = *(const float4*)(s + off);
  ushort4 o4 = { f2b(f.x), f2b(f.y), f2b(f.z), f2b(f.w) };
  *(ushort4*)(d + off) = o4;
}

// ---------------------------------------------------------------------------
// Fused QKV projection (unchanged from round 7, except Q pre-scale now
// 0.125*log2(e) so attention scores land in the exp2 domain).
// ---------------------------------------------------------------------------
__global__ __launch_bounds__(512) void gemm_qkv(
    const ushort* __restrict__ X,
    const ushort* __restrict__ Wq, const ushort* __restrict__ Wk, const ushort* __restrict__ Wv,
    ushort* __restrict__ Q, ushort* __restrict__ K, ushort* __restrict__ Vt,
    const int* __restrict__ pos)
{
  __shared__ __align__(16) char As[2][16384];
  __shared__ __align__(16) char Bs[2][16384];

  const int id  = blockIdx.x;          // 768 blocks
  const int xcd = id & 7;
  const int i   = id >> 3;             // 0..95
  const int mt  = xcd * 4 + (i & 3);   // 0..31
  const int nt  = i >> 2;              // 0..23
  const int m0  = mt * 128;
  const int nG  = nt * 128;
  const int z   = nG >> 10;            // 0:Q 1:K 2:V
  const int n0  = nG & 1023;
  const ushort* W = (z == 0) ? Wq : (z == 1) ? Wk : Wv;

  const int tid  = threadIdx.x;
  const int lane = tid & 63;
  const int w    = tid >> 6;           // 0..7
  const int wm   = (w >> 2) * 64;
  const int wn   = (w & 3) * 32;
  const int li   = lane & 15;
  const int g    = lane >> 4;

  f32x4 acc[4][2] = {};

  auto stage = [&](int t, int buf) {
    const int k0 = t * 64;
    #pragma unroll
    for (int it = 0; it < 2; ++it) {
      const int L  = w * 2048 + it * 1024 + lane * 16;
      const int r  = L >> 7;
      const int sc = ((L >> 4) & 7) ^ (r & 7);
      gll16(X + (size_t)(m0 + r) * DM + k0 + sc * 8, &As[buf][w * 2048 + it * 1024]);
      gll16(W + (size_t)(n0 + r) * DM + k0 + sc * 8, &Bs[buf][w * 2048 + it * 1024]);
    }
  };

  auto compute = [&](int buf) {
    #pragma unroll
    for (int ks = 0; ks < 2; ++ks) {
      bf16x8 af[4], bfr[2];
      #pragma unroll
      for (int mf = 0; mf < 4; ++mf) {
        const int row = wm + mf * 16 + li;
        af[mf] = *(const bf16x8*)(&As[buf][row * 128 + (((ks * 4 + g) ^ (row & 7)) << 4)]);
      }
      #pragma unroll
      for (int nf = 0; nf < 2; ++nf) {
        const int row = wn + nf * 16 + li;
        bfr[nf] = *(const bf16x8*)(&Bs[buf][row * 128 + (((ks * 4 + g) ^ (row & 7)) << 4)]);
      }
      #pragma unroll
      for (int mf = 0; mf < 4; ++mf)
        #pragma unroll
        for (int nf = 0; nf < 2; ++nf)
          acc[mf][nf] = __builtin_amdgcn_mfma_f32_16x16x32_bf16(af[mf], bfr[nf], acc[mf][nf], 0, 0, 0);
    }
  };

  stage(0, 0);
  for (int t = 0; t < 16; ++t) {
    if (t < 15) {
      stage(t + 1, (t + 1) & 1);
      __builtin_amdgcn_sched_barrier(0);
      asm volatile("s_waitcnt vmcnt(4)" ::: "memory");
    } else {
      asm volatile("s_waitcnt vmcnt(0)" ::: "memory");
    }
    __builtin_amdgcn_s_barrier();
    __builtin_amdgcn_sched_barrier(0);
    compute(t & 1);
    __builtin_amdgcn_sched_barrier(0);
    __builtin_amdgcn_s_barrier();
  }

  #pragma unroll
  for (int nf = 0; nf < 2; ++nf) {
    const int n = n0 + wn + nf * 16 + li;
    const int h = n >> 6;
    const int d = n & 63;
    if (z == 2) {
      #pragma unroll
      for (int mf = 0; mf < 4; ++mf) {
        const int m  = m0 + wm + mf * 16 + g * 4;
        const int b  = m >> 11;
        const int s2 = m & (SEQ - 1);
        ushort4 pk = { f2b(acc[mf][nf][0]), f2b(acc[mf][nf][1]),
                       f2b(acc[mf][nf][2]), f2b(acc[mf][nf][3]) };
        *(ushort4*)(Vt + (((size_t)b * NH + h) * DKH + d) * SEQ + s2) = pk;
      }
    } else {
      ushort* DST = (z == 0) ? Q : K;
      const float freq = __expf(-(float)(d >> 1) * 0.2878231366242557f);
      #pragma unroll
      for (int mf = 0; mf < 4; ++mf) {
        #pragma unroll
        for (int r = 0; r < 4; ++r) {
          const int m  = m0 + wm + mf * 16 + g * 4 + r;
          const int b  = m >> 11;
          const int s2 = m & (SEQ - 1);
          const float ang = (float)pos[s2] * freq;
          float sn, cs;
          __sincosf(ang, &sn, &cs);
          const float v1 = acc[mf][nf][r];
          const float v2 = __shfl_xor(v1, 1);
          float ov = (d & 1) ? (v2 * sn + v1 * cs)
                             : (v1 * cs - v2 * sn);
          if (z == 0) ov *= 0.1803368801111204f;   // 0.125 * log2(e)
          DST[(((size_t)b * NH + h) * SEQ + s2) * DKH + d] = f2b(ov);
        }
      }
    }
  }
}

// ---------------------------------------------------------------------------
// Wo projection (unchanged from round 7).
// ---------------------------------------------------------------------------
__global__ __launch_bounds__(512) void gemm_wo(
    const ushort* __restrict__ A, const ushort* __restrict__ W,
    float* __restrict__ out)
{
  __shared__ __align__(16) char As[2][16384];
  __shared__ __align__(16) char Bs[2][16384];

  const int id  = blockIdx.x;          // 256 blocks
  const int xcd = id & 7;
  const int i   = id >> 3;
  const int mt  = xcd * 4 + (i & 3);
  const int nt  = i >> 2;
  const int m0  = mt * 128;
  const int n0  = nt * 128;

  const int tid  = threadIdx.x;
  const int lane = tid & 63;
  const int w    = tid >> 6;
  const int wm   = (w >> 2) * 64;
  const int wn   = (w & 3) * 32;
  const int li   = lane & 15;
  const int g    = lane >> 4;

  f32x4 acc[4][2] = {};

  auto stage = [&](int t, int buf) {
    const int k0 = t * 64;
    #pragma unroll
    for (int it = 0; it < 2; ++it) {
      const int L  = w * 2048 + it * 1024 + lane * 16;
      const int r  = L >> 7;
      const int sc = ((L >> 4) & 7) ^ (r & 7);
      gll16(A + (size_t)(m0 + r) * DM + k0 + sc * 8, &As[buf][w * 2048 + it * 1024]);
      gll16(W + (size_t)(n0 + r) * DM + k0 + sc * 8, &Bs[buf][w * 2048 + it * 1024]);
    }
  };

  auto compute = [&](int buf) {
    #pragma unroll
    for (int ks = 0; ks < 2; ++ks) {
      bf16x8 af[4], bfr[2];
      #pragma unroll
      for (int mf = 0; mf < 4; ++mf) {
        const int row = wm + mf * 16 + li;
        af[mf] = *(const bf16x8*)(&As[buf][row * 128 + (((ks * 4 + g) ^ (row & 7)) << 4)]);
      }
      #pragma unroll
      for (int nf = 0; nf < 2; ++nf) {
        const int row = wn + nf * 16 + li;
        bfr[nf] = *(const bf16x8*)(&Bs[buf][row * 128 + (((ks * 4 + g) ^ (row & 7)) << 4)]);
      }
      #pragma unroll
      for (int mf = 0; mf < 4; ++mf)
        #pragma unroll
        for (int nf = 0; nf < 2; ++nf)
          acc[mf][nf] = __builtin_amdgcn_mfma_f32_16x16x32_bf16(af[mf], bfr[nf], acc[mf][nf], 0, 0, 0);
    }
  };

  stage(0, 0);
  for (int t = 0; t < 16; ++t) {
    if (t < 15) {
      stage(t + 1, (t + 1) & 1);
      __builtin_amdgcn_sched_barrier(0);
      asm volatile("s_waitcnt vmcnt(4)" ::: "memory");
    } else {
      asm volatile("s_waitcnt vmcnt(0)" ::: "memory");
    }
    __builtin_amdgcn_s_barrier();
    __builtin_amdgcn_sched_barrier(0);
    compute(t & 1);
    __builtin_amdgcn_sched_barrier(0);
    __builtin_amdgcn_s_barrier();
  }

  #pragma unroll
  for (int nf = 0; nf < 2; ++nf)
    #pragma unroll
    for (int mf = 0; mf < 4; ++mf)
      #pragma unroll
      for (int r = 0; r < 4; ++r)
        out[(size_t)(m0 + wm + mf * 16 + g * 4 + r) * DM + n0 + wn + nf * 16 + li] = acc[mf][nf][r];
}

// ---------------------------------------------------------------------------
// Causal flash attention, bf16 MFMA, exp2 domain.
// Per-CU balanced dispatch: blocks landing on one CU get qb = {j, 31-j, j,
// 31-j} -> exactly 66 kv-tile-trips per CU (was 4x same qb = up to 128).
// bh = s*8+xcd keeps each head's K/V pinned to one XCD's L2.
// Diagonal-only masking, defer-max (THR=8, log2 domain), cvt_pk P-pack,
// raw v_exp_f32, setprio around MFMA clusters.
// ---------------------------------------------------------------------------
__global__ __launch_bounds__(256) void attn(
    const ushort* __restrict__ Q, const ushort* __restrict__ K,
    const ushort* __restrict__ Vt, ushort* __restrict__ AO)
{
  __shared__ __align__(16) char KsB[2][8192];
  __shared__ __align__(16) char VsB[2][8192];
  __shared__ __align__(16) char Ps[8192];

  const int tid  = threadIdx.x;
  const int lane = tid & 63;
  const int w    = tid >> 6;
  const int li   = lane & 15;
  const int g    = lane >> 4;

  const int bx  = blockIdx.x;          // 1024 blocks
  const int xcd = bx & 7;
  const int idx = bx >> 3;             // 0..127
  const int j   = idx >> 2;            // 0..31 (CU slot within XCD)
  const int s   = idx & 3;
  const int qb  = (s & 1) ? (31 - j) : j;   // complementary pairing per CU
  const int bh  = s * 8 + xcd;
  const int q0b = qb * 64;
  const int n   = qb + 1;
  const int q0w = q0b + w * 16;

  const ushort* Qb = Q  + (size_t)bh * SEQ * DKH;
  const ushort* Kb = K  + (size_t)bh * SEQ * DKH;
  const ushort* Vb = Vt + (size_t)bh * DKH * SEQ;
  char* Pw = Ps + w * 2048;

  const bf16x8 qf0 = *(const bf16x8*)(Qb + (size_t)(q0w + li) * DKH + g * 8);
  const bf16x8 qf1 = *(const bf16x8*)(Qb + (size_t)(q0w + li) * DKH + 32 + g * 8);

  f32x4 o[4] = {};
  float m_ = -INFINITY, l_ = 0.f;

  auto stage = [&](int kt, int buf) {
    const int k0 = kt * 64;
    #pragma unroll
    for (int it = 0; it < 2; ++it) {
      const int L  = w * 2048 + it * 1024 + lane * 16;
      const int r  = L >> 7;
      const int sc = ((L >> 4) & 7) ^ (r & 7);
      gll16(Kb + (size_t)(k0 + r) * DKH + sc * 8, &KsB[buf][w * 2048 + it * 1024]);
      gll16(Vb + (size_t)r * SEQ + k0 + sc * 8,   &VsB[buf][w * 2048 + it * 1024]);
    }
  };

  auto computeT = [&](int t, bool diag) {
    const int k0 = t * 64;
    const char* Kc = KsB[t & 1];
    const char* Vc = VsB[t & 1];

    // S^T = K Q^T (scores already in log2 domain via Q pre-scale)
    f32x4 st[4] = {};
    __builtin_amdgcn_s_setprio(1);
    #pragma unroll
    for (int nf = 0; nf < 4; ++nf) {
      const int row = nf * 16 + li;
      bf16x8 kfa = *(const bf16x8*)(Kc + row * 128 + (((0 + g) ^ (row & 7)) << 4));
      bf16x8 kfb = *(const bf16x8*)(Kc + row * 128 + (((4 + g) ^ (row & 7)) << 4));
      st[nf] = __builtin_amdgcn_mfma_f32_16x16x32_bf16(kfa, qf0, st[nf], 0, 0, 0);
      st[nf] = __builtin_amdgcn_mfma_f32_16x16x32_bf16(kfb, qf1, st[nf], 0, 0, 0);
    }
    __builtin_amdgcn_s_setprio(0);

    if (diag) {                        // mask only ever bites on the diagonal tile
      #pragma unroll
      for (int nf = 0; nf < 4; ++nf)
        #pragma unroll
        for (int r = 0; r < 4; ++r)
          if (k0 + nf * 16 + g * 4 + r > q0w + li) st[nf][r] = -1e30f;
    }

    // lane-local row max (row q = q0w + li)
    float mx = fmaxf(fmaxf(fmaxf(st[0][0], st[0][1]), fmaxf(st[0][2], st[0][3])),
                     fmaxf(fmaxf(st[1][0], st[1][1]), fmaxf(st[1][2], st[1][3])));
    mx = fmaxf(mx, fmaxf(fmaxf(fmaxf(st[2][0], st[2][1]), fmaxf(st[2][2], st[2][3])),
                         fmaxf(fmaxf(st[3][0], st[3][1]), fmaxf(st[3][2], st[3][3]))));
    mx = fmaxf(mx, __shfl_xor(mx, 16));
    mx = fmaxf(mx, __shfl_xor(mx, 32));

    // defer-max: skip rescale when no row grew by more than 8 (p <= 2^8)
    const bool rescale = !__all(mx - m_ <= 8.0f);
    float al = 1.0f;
    if (rescale) {
      const float newm = fmaxf(m_, mx);
      al = exp2_fast(m_ - newm);
      m_ = newm;
    }

    float p[4][4];
    float rs = 0.f;
    #pragma unroll
    for (int nf = 0; nf < 4; ++nf)
      #pragma unroll
      for (int r = 0; r < 4; ++r) {
        p[nf][r] = exp2_fast(st[nf][r] - m_);
        rs += p[nf][r];
      }
    rs += __shfl_xor(rs, 16);
    rs += __shfl_xor(rs, 32);

    if (rescale) {
      l_ = l_ * al + rs;
      float alr[4];
      #pragma unroll
      for (int r = 0; r < 4; ++r) alr[r] = __shfl(al, g * 4 + r);
      #pragma unroll
      for (int nf = 0; nf < 4; ++nf)
        #pragma unroll
        for (int r = 0; r < 4; ++r) o[nf][r] *= alr[r];
    } else {
      l_ += rs;
    }

    // P -> wave-private LDS (transpose to A-frag layout), packed via cvt_pk
    #pragma unroll
    for (int nf = 0; nf < 4; ++nf) {
      uint2 pv = { cvt_pk(p[nf][0], p[nf][1]), cvt_pk(p[nf][2], p[nf][3]) };
      const int cw = nf * 2 + (g >> 1);
      *(uint2*)(Pw + li * 128 + ((cw ^ (li & 7)) << 4) + ((g & 1) << 3)) = pv;
    }
    bf16x8 pf0 = *(const bf16x8*)(Pw + li * 128 + (((0 + g) ^ (li & 7)) << 4));
    bf16x8 pf1 = *(const bf16x8*)(Pw + li * 128 + (((4 + g) ^ (li & 7)) << 4));

    // O += P V
    __builtin_amdgcn_s_setprio(1);
    #pragma unroll
    for (int nf = 0; nf < 4; ++nf) {
      const int row = nf * 16 + li;
      bf16x8 vfa = *(const bf16x8*)(Vc + row * 128 + (((0 + g) ^ (row & 7)) << 4));
      bf16x8 vfb = *(const bf16x8*)(Vc + row * 128 + (((4 + g) ^ (row & 7)) << 4));
      o[nf] = __builtin_amdgcn_mfma_f32_16x16x32_bf16(pf0, vfa, o[nf], 0, 0, 0);
      o[nf] = __builtin_amdgcn_mfma_f32_16x16x32_bf16(pf1, vfb, o[nf], 0, 0, 0);
    }
    __builtin_amdgcn_s_setprio(0);
  };

  stage(0, 0);
  for (int t = 0; t < n; ++t) {
    if (t + 1 < n) {
      stage(t + 1, (t + 1) & 1);
      __builtin_amdgcn_sched_barrier(0);
      asm volatile("s_waitcnt vmcnt(4)" ::: "memory");
    } else {
      asm volatile("s_waitcnt vmcnt(0)" ::: "memory");
    }
    __builtin_amdgcn_s_barrier();
    __builtin_amdgcn_sched_barrier(0);
    computeT(t, t == n - 1);
    __builtin_amdgcn_sched_barrier(0);
    __builtin_amdgcn_s_barrier();
  }

  const float inv = 1.0f / l_;
  float ir[4];
  #pragma unroll
  for (int r = 0; r < 4; ++r) ir[r] = __shfl(inv, g * 4 + r);

  const int b = bh >> 4, h = bh & 15;
  #pragma unroll
  for (int nf = 0; nf < 4; ++nf)
    #pragma unroll
    for (int r = 0; r < 4; ++r) {
      const int q = q0w + g * 4 + r;
      AO[((size_t)b * SEQ + q) * DM + h * DKH + nf * 16 + li] = f2b(o[nf][r] * ir[r]);
    }
}

// ---------------------------------------------------------------------------
extern "C" void kernel_launch(void* const* d_in, const int* in_sizes, int n_in,
                              void* d_out, int out_size, void* d_ws, size_t ws_size,
                              hipStream_t stream)
{
  const float* x   = (const float*)d_in[0];
  const int*   pos = (const int*)  d_in[1];
  const float* Wq  = (const float*)d_in[2];
  const float* Wk  = (const float*)d_in[3];
  const float* Wv  = (const float*)d_in[4];
  const float* Wo  = (const float*)d_in[5];
  float* out = (float*)d_out;

  ushort* ws  = (ushort*)d_ws;
  ushort* xb  = ws;                    // 4M
  ushort* wqb = xb  + 4194304;         // 1M each
  ushort* wkb = wqb + 1048576;
  ushort* wvb = wkb + 1048576;
  ushort* wob = wvb + 1048576;
  ushort* Qb  = wob + 1048576;         // 4M each
  ushort* Kb  = Qb  + 4194304;
  ushort* Vtb = Kb  + 4194304;
  ushort* AOb = Vtb + 4194304;

  cvt_all<<<8192, 256, 0, stream>>>(x, Wq, Wk, Wv, Wo, xb, wqb, wkb, wvb, wob);
  gemm_qkv<<<768, 512, 0, stream>>>(xb, wqb, wkb, wvb, Qb, Kb, Vtb, pos);
  attn<<<1024, 256, 0, stream>>>(Qb, Kb, Vtb, AOb);
  gemm_wo<<<256, 512, 0, stream>>>(AOb, wob, out);
}

// Round 9
// 108.450 us; speedup vs baseline: 13.2272x; 1.0474x over previous
//
#include <hip/hip_runtime.h>
#include <math.h>

#define SEQ 2048
#define NH  16
#define DKH 64
#define DM  1024
#define MR  4096   // BATCH*SEQ

using bf16x8 = __attribute__((ext_vector_type(8))) short;
using f32x4  = __attribute__((ext_vector_type(4))) float;

__device__ __forceinline__ ushort f2b(float f) {
  unsigned u = __float_as_uint(f);
  return (ushort)((u + 0x7fffu + ((u >> 16) & 1u)) >> 16);
}

__device__ __forceinline__ float exp2_fast(float x) {
  float r; asm("v_exp_f32 %0, %1" : "=v"(r) : "v"(x)); return r;
}

__device__ __forceinline__ unsigned cvt_pk(float lo, float hi) {
  unsigned r; asm("v_cvt_pk_bf16_f32 %0, %1, %2" : "=v"(r) : "v"(lo), "v"(hi));
  return r;
}

__device__ __forceinline__ void gll16(const void* g, void* l) {
  __builtin_amdgcn_global_load_lds(
      (const __attribute__((address_space(1))) void*)g,
      (__attribute__((address_space(3))) void*)l, 16, 0, 0);
}

// ---------------------------------------------------------------------------
// fp32 -> bf16 conversion of x and the 4 weight matrices (one launch)
// ---------------------------------------------------------------------------
__global__ __launch_bounds__(256) void cvt_all(
    const float* __restrict__ x,  const float* __restrict__ wq,
    const float* __restrict__ wk, const float* __restrict__ wv,
    const float* __restrict__ wo,
    ushort* __restrict__ xb,  ushort* __restrict__ wqb, ushort* __restrict__ wkb,
    ushort* __restrict__ wvb, ushort* __restrict__ wob)
{
  size_t e = ((size_t)blockIdx.x * 256 + threadIdx.x) * 4;
  const float* s; ushort* d; size_t off;
  if      (e < 4194304) { s = x;  d = xb;  off = e; }
  else if (e < 5242880) { s = wq; d = wqb; off = e - 4194304; }
  else if (e < 6291456) { s = wk; d = wkb; off = e - 5242880; }
  else if (e < 7340032) { s = wv; d = wvb; off = e - 6291456; }
  else                  { s = wo; d = wob; off = e - 7340032; }
  float4 f = *(const float4*)(s + off);
  ushort4 o4 = { f2b(f.x), f2b(f.y), f2b(f.z), f2b(f.w) };
  *(ushort4*)(d + off) = o4;
}

// ---------------------------------------------------------------------------
// Fused QKV projection (unchanged from round 8; Q pre-scale 0.125*log2(e)).
// ---------------------------------------------------------------------------
__global__ __launch_bounds__(512) void gemm_qkv(
    const ushort* __restrict__ X,
    const ushort* __restrict__ Wq, const ushort* __restrict__ Wk, const ushort* __restrict__ Wv,
    ushort* __restrict__ Q, ushort* __restrict__ K, ushort* __restrict__ Vt,
    const int* __restrict__ pos)
{
  __shared__ __align__(16) char As[2][16384];
  __shared__ __align__(16) char Bs[2][16384];

  const int id  = blockIdx.x;          // 768 blocks
  const int xcd = id & 7;
  const int i   = id >> 3;             // 0..95
  const int mt  = xcd * 4 + (i & 3);   // 0..31
  const int nt  = i >> 2;              // 0..23
  const int m0  = mt * 128;
  const int nG  = nt * 128;
  const int z   = nG >> 10;            // 0:Q 1:K 2:V
  const int n0  = nG & 1023;
  const ushort* W = (z == 0) ? Wq : (z == 1) ? Wk : Wv;

  const int tid  = threadIdx.x;
  const int lane = tid & 63;
  const int w    = tid >> 6;           // 0..7
  const int wm   = (w >> 2) * 64;
  const int wn   = (w & 3) * 32;
  const int li   = lane & 15;
  const int g    = lane >> 4;

  f32x4 acc[4][2] = {};

  auto stage = [&](int t, int buf) {
    const int k0 = t * 64;
    #pragma unroll
    for (int it = 0; it < 2; ++it) {
      const int L  = w * 2048 + it * 1024 + lane * 16;
      const int r  = L >> 7;
      const int sc = ((L >> 4) & 7) ^ (r & 7);
      gll16(X + (size_t)(m0 + r) * DM + k0 + sc * 8, &As[buf][w * 2048 + it * 1024]);
      gll16(W + (size_t)(n0 + r) * DM + k0 + sc * 8, &Bs[buf][w * 2048 + it * 1024]);
    }
  };

  auto compute = [&](int buf) {
    #pragma unroll
    for (int ks = 0; ks < 2; ++ks) {
      bf16x8 af[4], bfr[2];
      #pragma unroll
      for (int mf = 0; mf < 4; ++mf) {
        const int row = wm + mf * 16 + li;
        af[mf] = *(const bf16x8*)(&As[buf][row * 128 + (((ks * 4 + g) ^ (row & 7)) << 4)]);
      }
      #pragma unroll
      for (int nf = 0; nf < 2; ++nf) {
        const int row = wn + nf * 16 + li;
        bfr[nf] = *(const bf16x8*)(&Bs[buf][row * 128 + (((ks * 4 + g) ^ (row & 7)) << 4)]);
      }
      #pragma unroll
      for (int mf = 0; mf < 4; ++mf)
        #pragma unroll
        for (int nf = 0; nf < 2; ++nf)
          acc[mf][nf] = __builtin_amdgcn_mfma_f32_16x16x32_bf16(af[mf], bfr[nf], acc[mf][nf], 0, 0, 0);
    }
  };

  stage(0, 0);
  for (int t = 0; t < 16; ++t) {
    if (t < 15) {
      stage(t + 1, (t + 1) & 1);
      __builtin_amdgcn_sched_barrier(0);
      asm volatile("s_waitcnt vmcnt(4)" ::: "memory");
    } else {
      asm volatile("s_waitcnt vmcnt(0)" ::: "memory");
    }
    __builtin_amdgcn_s_barrier();
    __builtin_amdgcn_sched_barrier(0);
    compute(t & 1);
    __builtin_amdgcn_sched_barrier(0);
    __builtin_amdgcn_s_barrier();
  }

  #pragma unroll
  for (int nf = 0; nf < 2; ++nf) {
    const int n = n0 + wn + nf * 16 + li;
    const int h = n >> 6;
    const int d = n & 63;
    if (z == 2) {
      #pragma unroll
      for (int mf = 0; mf < 4; ++mf) {
        const int m  = m0 + wm + mf * 16 + g * 4;
        const int b  = m >> 11;
        const int s2 = m & (SEQ - 1);
        ushort4 pk = { f2b(acc[mf][nf][0]), f2b(acc[mf][nf][1]),
                       f2b(acc[mf][nf][2]), f2b(acc[mf][nf][3]) };
        *(ushort4*)(Vt + (((size_t)b * NH + h) * DKH + d) * SEQ + s2) = pk;
      }
    } else {
      ushort* DST = (z == 0) ? Q : K;
      const float freq = __expf(-(float)(d >> 1) * 0.2878231366242557f);
      #pragma unroll
      for (int mf = 0; mf < 4; ++mf) {
        #pragma unroll
        for (int r = 0; r < 4; ++r) {
          const int m  = m0 + wm + mf * 16 + g * 4 + r;
          const int b  = m >> 11;
          const int s2 = m & (SEQ - 1);
          const float ang = (float)pos[s2] * freq;
          float sn, cs;
          __sincosf(ang, &sn, &cs);
          const float v1 = acc[mf][nf][r];
          const float v2 = __shfl_xor(v1, 1);
          float ov = (d & 1) ? (v2 * sn + v1 * cs)
                             : (v1 * cs - v2 * sn);
          if (z == 0) ov *= 0.1803368801111204f;   // 0.125 * log2(e)
          DST[(((size_t)b * NH + h) * SEQ + s2) * DKH + d] = f2b(ov);
        }
      }
    }
  }
}

// ---------------------------------------------------------------------------
// Wo projection (unchanged from round 8).
// ---------------------------------------------------------------------------
__global__ __launch_bounds__(512) void gemm_wo(
    const ushort* __restrict__ A, const ushort* __restrict__ W,
    float* __restrict__ out)
{
  __shared__ __align__(16) char As[2][16384];
  __shared__ __align__(16) char Bs[2][16384];

  const int id  = blockIdx.x;          // 256 blocks
  const int xcd = id & 7;
  const int i   = id >> 3;
  const int mt  = xcd * 4 + (i & 3);
  const int nt  = i >> 2;
  const int m0  = mt * 128;
  const int n0  = nt * 128;

  const int tid  = threadIdx.x;
  const int lane = tid & 63;
  const int w    = tid >> 6;
  const int wm   = (w >> 2) * 64;
  const int wn   = (w & 3) * 32;
  const int li   = lane & 15;
  const int g    = lane >> 4;

  f32x4 acc[4][2] = {};

  auto stage = [&](int t, int buf) {
    const int k0 = t * 64;
    #pragma unroll
    for (int it = 0; it < 2; ++it) {
      const int L  = w * 2048 + it * 1024 + lane * 16;
      const int r  = L >> 7;
      const int sc = ((L >> 4) & 7) ^ (r & 7);
      gll16(A + (size_t)(m0 + r) * DM + k0 + sc * 8, &As[buf][w * 2048 + it * 1024]);
      gll16(W + (size_t)(n0 + r) * DM + k0 + sc * 8, &Bs[buf][w * 2048 + it * 1024]);
    }
  };

  auto compute = [&](int buf) {
    #pragma unroll
    for (int ks = 0; ks < 2; ++ks) {
      bf16x8 af[4], bfr[2];
      #pragma unroll
      for (int mf = 0; mf < 4; ++mf) {
        const int row = wm + mf * 16 + li;
        af[mf] = *(const bf16x8*)(&As[buf][row * 128 + (((ks * 4 + g) ^ (row & 7)) << 4)]);
      }
      #pragma unroll
      for (int nf = 0; nf < 2; ++nf) {
        const int row = wn + nf * 16 + li;
        bfr[nf] = *(const bf16x8*)(&Bs[buf][row * 128 + (((ks * 4 + g) ^ (row & 7)) << 4)]);
      }
      #pragma unroll
      for (int mf = 0; mf < 4; ++mf)
        #pragma unroll
        for (int nf = 0; nf < 2; ++nf)
          acc[mf][nf] = __builtin_amdgcn_mfma_f32_16x16x32_bf16(af[mf], bfr[nf], acc[mf][nf], 0, 0, 0);
    }
  };

  stage(0, 0);
  for (int t = 0; t < 16; ++t) {
    if (t < 15) {
      stage(t + 1, (t + 1) & 1);
      __builtin_amdgcn_sched_barrier(0);
      asm volatile("s_waitcnt vmcnt(4)" ::: "memory");
    } else {
      asm volatile("s_waitcnt vmcnt(0)" ::: "memory");
    }
    __builtin_amdgcn_s_barrier();
    __builtin_amdgcn_sched_barrier(0);
    compute(t & 1);
    __builtin_amdgcn_sched_barrier(0);
    __builtin_amdgcn_s_barrier();
  }

  #pragma unroll
  for (int nf = 0; nf < 2; ++nf)
    #pragma unroll
    for (int mf = 0; mf < 4; ++mf)
      #pragma unroll
      for (int r = 0; r < 4; ++r)
        out[(size_t)(m0 + wm + mf * 16 + g * 4 + r) * DM + n0 + wn + nf * 16 + li] = acc[mf][nf][r];
}

// ---------------------------------------------------------------------------
// Causal flash attention, bf16 MFMA, exp2 domain, UNIFORM-WORK pair blocks.
// Block = (bh, pair p): processes q-tile (31-p), then q-tile p, each with its
// own online-softmax state. kv staged in 128-wide chunks (double-buffered):
// ceil((32-p)/2) + ceil((p+1)/2) = 17 staging trips for EVERY block -> any
// dispatch order is balanced; no tail, no drain. Prefetch pipeline runs
// across the segment boundary. 512 blocks, 2/CU (72KB LDS).
// ---------------------------------------------------------------------------
__global__ __launch_bounds__(256) void attn(
    const ushort* __restrict__ Q, const ushort* __restrict__ K,
    const ushort* __restrict__ Vt, ushort* __restrict__ AO)
{
  __shared__ __align__(16) char KsB[2][16384];   // 128 rows x 128B, swizzled
  __shared__ __align__(16) char VsB[2][16384];   // 64 d-rows x 256B, swizzled
  __shared__ __align__(16) char Ps[8192];        // 4 waves x 2KB P-transpose

  const int tid  = threadIdx.x;
  const int lane = tid & 63;
  const int w    = tid >> 6;
  const int li   = lane & 15;
  const int g    = lane >> 4;

  const int bx  = blockIdx.x;          // 512 blocks
  const int xcd = bx & 7;
  const int idx = bx >> 3;             // 0..63
  const int p   = idx >> 2;            // 0..15 (pair)
  const int s   = idx & 3;
  const int bh  = s * 8 + xcd;
  const int segA = 31 - p;             // heavy q-tile first
  const int segB = p;
  const int ncA = (segA + 2) >> 1;     // ceil((segA+1)/2) kv128 chunks
  const int ncB = (segB + 2) >> 1;
  const int nT  = ncA + ncB;           // == 17 for all blocks

  const ushort* Qb = Q  + (size_t)bh * SEQ * DKH;
  const ushort* Kb = K  + (size_t)bh * SEQ * DKH;
  const ushort* Vb = Vt + (size_t)bh * DKH * SEQ;
  char* Pw = Ps + w * 2048;
  const int b = bh >> 4, h = bh & 15;

  // Q fragments for both segments (B-role)
  const int qA = segA * 64 + w * 16;
  const int qB = segB * 64 + w * 16;
  const bf16x8 qfA0 = *(const bf16x8*)(Qb + (size_t)(qA + li) * DKH + g * 8);
  const bf16x8 qfA1 = *(const bf16x8*)(Qb + (size_t)(qA + li) * DKH + 32 + g * 8);
  const bf16x8 qfB0 = *(const bf16x8*)(Qb + (size_t)(qB + li) * DKH + g * 8);
  const bf16x8 qfB1 = *(const bf16x8*)(Qb + (size_t)(qB + li) * DKH + 32 + g * 8);

  f32x4 o[4] = {};
  float m_ = -INFINITY, l_ = 0.f;
  bf16x8 qf0 = qfA0, qf1 = qfA1;
  int seg = segA, q0w = qA;

  // stage kv128 chunk (trip i) into buffer buf: K 16KB + V 16KB, 8 gll16/wave
  auto stage = [&](int i, int buf) {
    const int c  = (i < ncA) ? i : i - ncA;
    const int k0 = c * 128;
    #pragma unroll
    for (int it = 0; it < 4; ++it) {
      const int L  = w * 4096 + it * 1024 + lane * 16;
      const int r  = L >> 7;                     // K row 0..127
      const int c3 = ((L >> 4) & 7) ^ (r & 7);
      gll16(Kb + (size_t)(k0 + r) * DKH + c3 * 8, &KsB[buf][w * 4096 + it * 1024]);
    }
    #pragma unroll
    for (int it = 0; it < 4; ++it) {
      const int L  = w * 4096 + it * 1024 + lane * 16;
      const int r  = L >> 8;                     // V d-row 0..63 (256B rows)
      const int lb = L & 255;
      const int j  = lb >> 7;                    // kv64 half
      const int c3 = ((lb >> 4) & 7) ^ (r & 7);
      gll16(Vb + (size_t)r * SEQ + k0 + j * 64 + c3 * 8, &VsB[buf][w * 4096 + it * 1024]);
    }
  };

  // compute one kv64 subtile t (chunk-half j) against current segment state
  auto computeT = [&](int t, int j, int buf) {
    const int k0 = t * 64;
    const char* Kc = &KsB[buf][j * 8192];
    const char* Vc = &VsB[buf][0];
    const int vjo = j * 128;

    f32x4 st[4] = {};
    __builtin_amdgcn_s_setprio(1);
    #pragma unroll
    for (int nf = 0; nf < 4; ++nf) {
      const int row = nf * 16 + li;
      bf16x8 kfa = *(const bf16x8*)(Kc + row * 128 + (((0 + g) ^ (row & 7)) << 4));
      bf16x8 kfb = *(const bf16x8*)(Kc + row * 128 + (((4 + g) ^ (row & 7)) << 4));
      st[nf] = __builtin_amdgcn_mfma_f32_16x16x32_bf16(kfa, qf0, st[nf], 0, 0, 0);
      st[nf] = __builtin_amdgcn_mfma_f32_16x16x32_bf16(kfb, qf1, st[nf], 0, 0, 0);
    }
    __builtin_amdgcn_s_setprio(0);

    if (t == seg) {                    // diagonal subtile: causal mask
      #pragma unroll
      for (int nf = 0; nf < 4; ++nf)
        #pragma unroll
        for (int r = 0; r < 4; ++r)
          if (k0 + nf * 16 + g * 4 + r > q0w + li) st[nf][r] = -1e30f;
    }

    float mx = fmaxf(fmaxf(fmaxf(st[0][0], st[0][1]), fmaxf(st[0][2], st[0][3])),
                     fmaxf(fmaxf(st[1][0], st[1][1]), fmaxf(st[1][2], st[1][3])));
    mx = fmaxf(mx, fmaxf(fmaxf(fmaxf(st[2][0], st[2][1]), fmaxf(st[2][2], st[2][3])),
                         fmaxf(fmaxf(st[3][0], st[3][1]), fmaxf(st[3][2], st[3][3]))));
    mx = fmaxf(mx, __shfl_xor(mx, 16));
    mx = fmaxf(mx, __shfl_xor(mx, 32));

    const bool rescale = !__all(mx - m_ <= 8.0f);
    float al = 1.0f;
    if (rescale) {
      const float newm = fmaxf(m_, mx);
      al = exp2_fast(m_ - newm);
      m_ = newm;
    }

    float pv[4][4];
    float rs = 0.f;
    #pragma unroll
    for (int nf = 0; nf < 4; ++nf)
      #pragma unroll
      for (int r = 0; r < 4; ++r) {
        pv[nf][r] = exp2_fast(st[nf][r] - m_);
        rs += pv[nf][r];
      }
    rs += __shfl_xor(rs, 16);
    rs += __shfl_xor(rs, 32);

    if (rescale) {
      l_ = l_ * al + rs;
      float alr[4];
      #pragma unroll
      for (int r = 0; r < 4; ++r) alr[r] = __shfl(al, g * 4 + r);
      #pragma unroll
      for (int nf = 0; nf < 4; ++nf)
        #pragma unroll
        for (int r = 0; r < 4; ++r) o[nf][r] *= alr[r];
    } else {
      l_ += rs;
    }

    #pragma unroll
    for (int nf = 0; nf < 4; ++nf) {
      uint2 pk = { cvt_pk(pv[nf][0], pv[nf][1]), cvt_pk(pv[nf][2], pv[nf][3]) };
      const int cw = nf * 2 + (g >> 1);
      *(uint2*)(Pw + li * 128 + ((cw ^ (li & 7)) << 4) + ((g & 1) << 3)) = pk;
    }
    bf16x8 pf0 = *(const bf16x8*)(Pw + li * 128 + (((0 + g) ^ (li & 7)) << 4));
    bf16x8 pf1 = *(const bf16x8*)(Pw + li * 128 + (((4 + g) ^ (li & 7)) << 4));

    __builtin_amdgcn_s_setprio(1);
    #pragma unroll
    for (int nf = 0; nf < 4; ++nf) {
      const int row = nf * 16 + li;
      bf16x8 vfa = *(const bf16x8*)(Vc + row * 256 + vjo + (((0 + g) ^ (row & 7)) << 4));
      bf16x8 vfb = *(const bf16x8*)(Vc + row * 256 + vjo + (((4 + g) ^ (row & 7)) << 4));
      o[nf] = __builtin_amdgcn_mfma_f32_16x16x32_bf16(pf0, vfa, o[nf], 0, 0, 0);
      o[nf] = __builtin_amdgcn_mfma_f32_16x16x32_bf16(pf1, vfb, o[nf], 0, 0, 0);
    }
    __builtin_amdgcn_s_setprio(0);
  };

  auto finalize = [&]() {
    const float inv = 1.0f / l_;
    float ir[4];
    #pragma unroll
    for (int r = 0; r < 4; ++r) ir[r] = __shfl(inv, g * 4 + r);
    #pragma unroll
    for (int nf = 0; nf < 4; ++nf)
      #pragma unroll
      for (int r = 0; r < 4; ++r) {
        const int q = q0w + g * 4 + r;
        AO[((size_t)b * SEQ + q) * DM + h * DKH + nf * 16 + li] = f2b(o[nf][r] * ir[r]);
      }
  };

  stage(0, 0);
  for (int i = 0; i < nT; ++i) {
    if (i + 1 < nT) {
      stage(i + 1, (i + 1) & 1);
      __builtin_amdgcn_sched_barrier(0);
      asm volatile("s_waitcnt vmcnt(8)" ::: "memory");   // trip i landed; i+1 in flight
    } else {
      asm volatile("s_waitcnt vmcnt(0)" ::: "memory");
    }
    __builtin_amdgcn_s_barrier();
    __builtin_amdgcn_sched_barrier(0);

    const int c = (i < ncA) ? i : i - ncA;
    #pragma unroll
    for (int j = 0; j < 2; ++j) {
      const int t = 2 * c + j;
      if (t <= seg) computeT(t, j, i & 1);   // block-uniform condition
    }

    __builtin_amdgcn_sched_barrier(0);
    __builtin_amdgcn_s_barrier();

    if (i == ncA - 1) {                      // segment A done -> write, reset
      finalize();
      #pragma unroll
      for (int nf = 0; nf < 4; ++nf) o[nf] = f32x4{0.f, 0.f, 0.f, 0.f};
      m_ = -INFINITY; l_ = 0.f;
      qf0 = qfB0; qf1 = qfB1;
      seg = segB; q0w = qB;
    }
  }
  finalize();
}

// ---------------------------------------------------------------------------
extern "C" void kernel_launch(void* const* d_in, const int* in_sizes, int n_in,
                              void* d_out, int out_size, void* d_ws, size_t ws_size,
                              hipStream_t stream)
{
  const float* x   = (const float*)d_in[0];
  const int*   pos = (const int*)  d_in[1];
  const float* Wq  = (const float*)d_in[2];
  const float* Wk  = (const float*)d_in[3];
  const float* Wv  = (const float*)d_in[4];
  const float* Wo  = (const float*)d_in[5];
  float* out = (float*)d_out;

  ushort* ws  = (ushort*)d_ws;
  ushort* xb  = ws;                    // 4M
  ushort* wqb = xb  + 4194304;         // 1M each
  ushort* wkb = wqb + 1048576;
  ushort* wvb = wkb + 1048576;
  ushort* wob = wvb + 1048576;
  ushort* Qb  = wob + 1048576;         // 4M each
  ushort* Kb  = Qb  + 4194304;
  ushort* Vtb = Kb  + 4194304;
  ushort* AOb = Vtb + 4194304;

  cvt_all<<<8192, 256, 0, stream>>>(x, Wq, Wk, Wv, Wo, xb, wqb, wkb, wvb, wob);
  gemm_qkv<<<768, 512, 0, stream>>>(xb, wqb, wkb, wvb, Qb, Kb, Vtb, pos);
  attn<<<512, 256, 0, stream>>>(Qb, Kb, Vtb, AOb);
  gemm_wo<<<256, 512, 0, stream>>>(AOb, wob, out);
}